// Round 11
// baseline (82.701 us; speedup 1.0000x reference)
//
#include <hip/hip_runtime.h>
#include <hip/hip_bf16.h>
#include <hip/hip_cooperative_groups.h>

namespace cg = cooperative_groups;

#define NQ     4000
#define DMODEL 256
#define NHEAD  8
#define NLVL   4
#define NPT    4
#define DHEAD  32
#define LENIN  37440
#define NOFF   384
#define NATT   128
#define NPROJ  512   // NOFF + NATT

#define NVBLK  (LENIN / 64)            // 585 value-role front jobs
#define NQBLK  ((NQ + 63) / 64)        // 63 row tiles for query-side GEMMs
#define NJF    (NVBLK + 2 * NQBLK)     // 711 front jobs
#define NJS    (NQ / 4)                // 1000 sampler jobs
#define NJO    (2 * NQBLK)             // 126 out jobs
#define LDH    40                      // padded LDS row (halfs) for GEMM tiles
#define LDSW   132                     // padded LDS row (halfs) for C bounce
#define SMEM_MAX 33536                 // sampler phase is the max

typedef _Float16 f16x8 __attribute__((ext_vector_type(8)));
typedef _Float16 f16x4 __attribute__((ext_vector_type(4)));
typedef float    f32x4 __attribute__((ext_vector_type(4)));

// ------------------------------------------------ phase A: weight transposes
static __device__ void do_cast(int job, char* smem,
    const float* __restrict__ wv, const float* __restrict__ wo,
    const float* __restrict__ wa, const float* __restrict__ wu,
    _Float16* __restrict__ wvT, _Float16* __restrict__ catT,
    _Float16* __restrict__ wuT)
{
    float (*t)[65] = (float (*)[65])smem;
    const int xt = job >> 2, kt = job & 3;
    const float* W; _Float16* WT; int ncols, col0, nbase;
    if (xt < 4)       { W = wv; WT = wvT;  ncols = 256; col0 = xt * 64;        nbase = col0; }
    else if (xt < 10) { W = wo; WT = catT; ncols = 384; col0 = (xt - 4) * 64;  nbase = col0; }
    else if (xt < 12) { W = wa; WT = catT; ncols = 128; col0 = (xt - 10) * 64; nbase = 384 + col0; }
    else              { W = wu; WT = wuT;  ncols = 256; col0 = (xt - 12) * 64; nbase = col0; }

    const int by = kt * 64;           // k-range
    const int tid = threadIdx.x;
    const int c = tid & 63, r0 = tid >> 6;
    #pragma unroll
    for (int i = 0; i < 16; ++i) {
        int r = r0 + i * 4;
        t[r][c] = W[(size_t)(by + r) * ncols + col0 + c];
    }
    __syncthreads();
    #pragma unroll
    for (int i = 0; i < 16; ++i) {
        int n = r0 + i * 4;
        WT[(size_t)(nbase + n) * DMODEL + by + c] = (_Float16)t[c][n];
    }
    __syncthreads();
}

// --------------------------------------------- phase B: merged front GEMM
static __device__ void do_front(int job, char* smem,
    const float* __restrict__ Aval, const float* __restrict__ query,
    const _Float16* __restrict__ wvT, const _Float16* __restrict__ catT,
    const float* __restrict__ bval, const float* __restrict__ boff,
    const float* __restrict__ batt,
    _Float16* __restrict__ valueH, _Float16* __restrict__ proj)
{
    _Float16 (*As)[LDH] = (_Float16 (*)[LDH])smem;                 // 64 x 40
    _Float16 (*Bs)[LDH] = (_Float16 (*)[LDH])(smem + 64 * LDH * 2);// 256 x 40

    const int tid  = threadIdx.x;
    const int wave = tid >> 6, lane = tid & 63;
    const int l15 = lane & 15, l16 = lane >> 4;

    const bool isval = (job < NVBLK);
    const float* A; const _Float16* BT; int brow, ncb, M;
    if (isval) { A = Aval;  BT = wvT;  brow = job * 64;  ncb = 0;  M = LENIN; }
    else       { int idx = job - NVBLK; A = query; BT = catT;
                 brow = (idx >> 1) * 64; ncb = (idx & 1) * 256; M = NQ; }

    const int arow = tid >> 2, akq = (tid & 3) * 8;
    int arg = brow + arow; if (arg >= M) arg = M - 1;
    const float* aptr = A + (size_t)arg * DMODEL + akq;

    const _Float16* bptr[4];
    int bn[4], bkc[4];
    #pragma unroll
    for (int j = 0; j < 4; ++j) {
        int id = tid + 256 * j;            // chunk id = n*4 + kc
        bn[j] = id >> 2; bkc[j] = (id & 3) * 8;
        bptr[j] = BT + (size_t)(ncb + bn[j]) * DMODEL + bkc[j];
    }

    f32x4 acc[4][4] = {};   // [mi][ni]
    float4 a0, a1;
    f16x8 bh[4];

    a0 = *(const float4*)(const void*)aptr;
    a1 = *(const float4*)(const void*)(aptr + 4);
    #pragma unroll
    for (int j = 0; j < 4; ++j) bh[j] = *(const f16x8*)bptr[j];

    for (int k0 = 0; k0 < DMODEL; k0 += 32) {
        {
            f16x8 h;
            h[0] = (_Float16)a0.x; h[1] = (_Float16)a0.y;
            h[2] = (_Float16)a0.z; h[3] = (_Float16)a0.w;
            h[4] = (_Float16)a1.x; h[5] = (_Float16)a1.y;
            h[6] = (_Float16)a1.z; h[7] = (_Float16)a1.w;
            *(f16x8*)&As[arow][akq] = h;
        }
        #pragma unroll
        for (int j = 0; j < 4; ++j) *(f16x8*)&Bs[bn[j]][bkc[j]] = bh[j];
        __syncthreads();

        if (k0 + 32 < DMODEL) {   // issue next K-step's loads before MFMA
            a0 = *(const float4*)(const void*)(aptr + k0 + 32);
            a1 = *(const float4*)(const void*)(aptr + k0 + 36);
            #pragma unroll
            for (int j = 0; j < 4; ++j) bh[j] = *(const f16x8*)(bptr[j] + k0 + 32);
        }

        f16x8 af[4], bf[4];
        #pragma unroll
        for (int mi = 0; mi < 4; ++mi)
            af[mi] = *(const f16x8*)&As[mi * 16 + l15][l16 * 8];
        #pragma unroll
        for (int ni = 0; ni < 4; ++ni)
            bf[ni] = *(const f16x8*)&Bs[wave * 64 + ni * 16 + l15][l16 * 8];
        #pragma unroll
        for (int mi = 0; mi < 4; ++mi)
            #pragma unroll
            for (int ni = 0; ni < 4; ++ni)
                acc[mi][ni] = __builtin_amdgcn_mfma_f32_16x16x32_f16(
                    af[mi], bf[ni], acc[mi][ni], 0, 0, 0);
        __syncthreads();
    }

    if (isval) {
        // ---- epilogue A: LDS bounce -> coalesced head-major stores
        _Float16 (*out_s)[LDSW] = (_Float16 (*)[LDSW])smem;
        const int cell = tid >> 2, dchunk = tid & 3;
        #pragma unroll
        for (int hh = 0; hh < 2; ++hh) {
            if ((wave >> 1) == hh) {
                int cb = (wave & 1) * 64;
                #pragma unroll
                for (int ni = 0; ni < 4; ++ni) {
                    int col = wave * 64 + ni * 16 + l15;
                    float b = bval[col];
                    #pragma unroll
                    for (int mi = 0; mi < 4; ++mi)
                        #pragma unroll
                        for (int j = 0; j < 4; ++j)
                            out_s[mi * 16 + l16 * 4 + j][cb + ni * 16 + l15] =
                                (_Float16)(acc[mi][ni][j] + b);
                }
            }
            __syncthreads();
            #pragma unroll
            for (int h2 = 0; h2 < 4; ++h2) {
                int h = hh * 4 + h2;
                f16x4 lo = *(const f16x4*)&out_s[cell][h2 * 32 + dchunk * 8];
                f16x4 hi = *(const f16x4*)&out_s[cell][h2 * 32 + dchunk * 8 + 4];
                size_t base = ((size_t)h * LENIN + brow + cell) * DHEAD + dchunk * 8;
                *(f16x4*)&valueH[base]     = lo;
                *(f16x4*)&valueH[base + 4] = hi;
            }
            __syncthreads();
        }
    } else {
        // ---- epilogue B: f16 stores to proj
        #pragma unroll
        for (int ni = 0; ni < 4; ++ni) {
            int col = ncb + wave * 64 + ni * 16 + l15;
            float b = (col < NOFF) ? boff[col] : batt[col - NOFF];
            #pragma unroll
            for (int mi = 0; mi < 4; ++mi)
                #pragma unroll
                for (int j = 0; j < 4; ++j) {
                    int row = brow + mi * 16 + l16 * 4 + j;
                    if (row < NQ)
                        proj[(size_t)row * NPROJ + col] = (_Float16)(acc[mi][ni][j] + b);
                }
        }
        __syncthreads();
    }
}

// -------------------------------------- phase C: loc+softmax+corners+gather
static __device__ void do_sample(int job, char* smem,
    const _Float16* __restrict__ value, const _Float16* __restrict__ proj,
    const float* __restrict__ refpts, _Float16* __restrict__ oat)
{
    float*    loc_s = (float*)smem;                    // [4][384]
    float*    aw_s  = (float*)(smem + 6144);           // [4][128]
    unsigned* ca_s  = (unsigned*)(smem + 8192);        // [4][1056]
    _Float16* cw_s  = (_Float16*)(smem + 25088);       // [4][1056]

    const int tid  = threadIdx.x;
    const int wv   = tid >> 6, lane = tid & 63;
    const int q    = job * 4 + wv;
    const _Float16* pq = proj + (size_t)q * NPROJ;

    // ---- phase 0: locations + softmax
    #pragma unroll
    for (int i = 0; i < 8; ++i) {
        int t = i * 64 + lane;
        float v = (float)pq[t];
        if (t < NOFF) {
            int t2 = t / 3, lvl = (t2 >> 2) & 3, c = t - t2 * 3;
            float norm = (float)(32 >> lvl);
            loc_s[wv * NOFF + t] = refpts[((size_t)q * NLVL + lvl) * 3 + c] + v / norm;
        } else {
            float m = v;
            #pragma unroll
            for (int o = 8; o >= 1; o >>= 1) m = fmaxf(m, __shfl_xor(m, o, 16));
            float e = expf(v - m);
            float s = e;
            #pragma unroll
            for (int o = 8; o >= 1; o >>= 1) s += __shfl_xor(s, o, 16);
            aw_s[wv * NATT + (t - NOFF)] = e / s;
        }
    }
    __syncthreads();

    // ---- phase 1: per-corner byte address (head-major) + weight
    #pragma unroll
    for (int i = 0; i < 16; ++i) {
        int id = i * 64 + lane;            // h*128 + pt*8 + c
        int h = id >> 7, pt = (id >> 3) & 15, c = id & 7;
        int lvl = pt >> 2;
        int S = 32 >> lvl;
        float Sf = (float)S;
        int base = (lvl == 0) ? 0 : (lvl == 1) ? 32768 : (lvl == 2) ? 36864 : 37376;

        float lx = loc_s[wv * NOFF + h * 48 + pt * 3 + 0];
        float ly = loc_s[wv * NOFF + h * 48 + pt * 3 + 1];
        float lz = loc_s[wv * NOFF + h * 48 + pt * 3 + 2];
        float aw = aw_s[wv * NATT + h * 16 + pt];

        float x = lx * Sf - 0.5f, y = ly * Sf - 0.5f, z = lz * Sf - 0.5f;
        float x0f = floorf(x), y0f = floorf(y), z0f = floorf(z);
        float fx = x - x0f, fy = y - y0f, fz = z - z0f;
        int dx = c & 1, dy = (c >> 1) & 1, dz = c >> 2;
        int xi = (int)x0f + dx, yi = (int)y0f + dy, zi = (int)z0f + dz;
        float wx = dx ? fx : 1.f - fx;
        float wy = dy ? fy : 1.f - fy;
        float wz = dz ? fz : 1.f - fz;
        bool valid = (unsigned)xi < (unsigned)S &&
                     (unsigned)yi < (unsigned)S &&
                     (unsigned)zi < (unsigned)S;
        int idx = (zi * S + yi) * S + xi;            // only meaningful if valid
        unsigned addr = valid ? (unsigned)(h * LENIN + base + idx) * 64u
                              : (unsigned)(h * LENIN) * 64u;   // hot dummy line
        float w = valid ? wx * wy * wz * aw : 0.f;
        ca_s[wv * 1056 + h * 132 + pt * 8 + c] = addr;
        cw_s[wv * 1056 + h * 132 + pt * 8 + c] = (_Float16)w;
    }
    __syncthreads();

    // ---- phase 2: gather, 16B per load
    const int h = lane >> 3, s = lane & 7;
    const int chunk = s & 3, half4 = (s >> 2) * 4;
    const char* vb = (const char*)value + chunk * 16;
    const unsigned* ca  = &ca_s[wv * 1056 + h * 132];
    const _Float16* cwp = &cw_s[wv * 1056 + h * 132];

    float acc[8] = {};
    #pragma unroll 4
    for (int pt = 0; pt < 16; ++pt) {
        uint4 a4 = *(const uint4*)&ca[pt * 8 + half4];
        f16x4 w4 = *(const f16x4*)&cwp[pt * 8 + half4];
        {
            f16x8 v = *(const f16x8*)(vb + a4.x); float w = (float)w4[0];
            #pragma unroll
            for (int j = 0; j < 8; ++j) acc[j] += w * (float)v[j];
        }
        {
            f16x8 v = *(const f16x8*)(vb + a4.y); float w = (float)w4[1];
            #pragma unroll
            for (int j = 0; j < 8; ++j) acc[j] += w * (float)v[j];
        }
        {
            f16x8 v = *(const f16x8*)(vb + a4.z); float w = (float)w4[2];
            #pragma unroll
            for (int j = 0; j < 8; ++j) acc[j] += w * (float)v[j];
        }
        {
            f16x8 v = *(const f16x8*)(vb + a4.w); float w = (float)w4[3];
            #pragma unroll
            for (int j = 0; j < 8; ++j) acc[j] += w * (float)v[j];
        }
    }
    // combine the two corner-halves (lanes s and s^4 own same channels)
    #pragma unroll
    for (int j = 0; j < 8; ++j) acc[j] += __shfl_xor(acc[j], 4);

    if (s < 4) {
        f16x8 r;
        #pragma unroll
        for (int j = 0; j < 8; ++j) r[j] = (_Float16)acc[j];
        *(f16x8*)&oat[(size_t)q * DMODEL + h * DHEAD + chunk * 8] = r;
    }
    __syncthreads();
}

// ------------------------------------------ phase D: output projection GEMM
static __device__ void do_out(int job, char* smem,
    const _Float16* __restrict__ A, const _Float16* __restrict__ BT,
    const float* __restrict__ bias, float* __restrict__ C)
{
    _Float16 (*As)[LDH] = (_Float16 (*)[LDH])smem;                 // 64 x 40
    _Float16 (*Bs)[LDH] = (_Float16 (*)[LDH])(smem + 64 * LDH * 2);// 128 x 40
    const int tid  = threadIdx.x;
    const int wave = tid >> 6, lane = tid & 63;
    const int brow = (job >> 1) * 64;
    const int bcol = (job & 1) * 128;
    const int l15 = lane & 15, l16 = lane >> 4;

    const int arow = tid >> 2, akq = (tid & 3) * 8;
    int arg = brow + arow; if (arg >= NQ) arg = NQ - 1;
    const _Float16* aptr = A + (size_t)arg * DMODEL + akq;

    const _Float16* bptr[2];
    int bn[2], bkc[2];
    #pragma unroll
    for (int j = 0; j < 2; ++j) {
        int id = tid + 256 * j;
        bn[j] = id >> 2; bkc[j] = (id & 3) * 8;
        bptr[j] = BT + (size_t)(bcol + bn[j]) * DMODEL + bkc[j];
    }

    f32x4 acc[4][2] = {};
    f16x8 ah, bh[2];
    ah = *(const f16x8*)(const void*)aptr;
    #pragma unroll
    for (int j = 0; j < 2; ++j) bh[j] = *(const f16x8*)bptr[j];

    for (int k0 = 0; k0 < DMODEL; k0 += 32) {
        *(f16x8*)&As[arow][akq] = ah;
        #pragma unroll
        for (int j = 0; j < 2; ++j) *(f16x8*)&Bs[bn[j]][bkc[j]] = bh[j];
        __syncthreads();

        if (k0 + 32 < DMODEL) {
            ah = *(const f16x8*)(const void*)(aptr + k0 + 32);
            #pragma unroll
            for (int j = 0; j < 2; ++j) bh[j] = *(const f16x8*)(bptr[j] + k0 + 32);
        }

        f16x8 af[4], bf[2];
        #pragma unroll
        for (int mi = 0; mi < 4; ++mi)
            af[mi] = *(const f16x8*)&As[mi * 16 + l15][l16 * 8];
        #pragma unroll
        for (int ni = 0; ni < 2; ++ni)
            bf[ni] = *(const f16x8*)&Bs[wave * 32 + ni * 16 + l15][l16 * 8];
        #pragma unroll
        for (int mi = 0; mi < 4; ++mi)
            #pragma unroll
            for (int ni = 0; ni < 2; ++ni)
                acc[mi][ni] = __builtin_amdgcn_mfma_f32_16x16x32_f16(
                    af[mi], bf[ni], acc[mi][ni], 0, 0, 0);
        __syncthreads();
    }

    #pragma unroll
    for (int ni = 0; ni < 2; ++ni) {
        int col = bcol + wave * 32 + ni * 16 + l15;
        float b = bias[col];
        #pragma unroll
        for (int mi = 0; mi < 4; ++mi)
            #pragma unroll
            for (int j = 0; j < 4; ++j) {
                int row = brow + mi * 16 + l16 * 4 + j;
                if (row < NQ)
                    C[(size_t)row * DMODEL + col] = acc[mi][ni][j] + b;
            }
    }
    __syncthreads();
}

// -------------------------------------------------- cooperative mega-kernel
__global__ __launch_bounds__(256, 2) void mega(
    const float* query, const float* refpts, const float* input_flatten,
    const float* w_value, const float* b_value, const float* w_off,
    const float* b_off, const float* w_attn, const float* b_attn,
    const float* w_out, const float* b_out,
    _Float16* valueH, _Float16* wvT, _Float16* catT, _Float16* wuT,
    _Float16* proj, _Float16* oatH, float* out)
{
    __shared__ __align__(16) char smem[SMEM_MAX];
    cg::grid_group grid = cg::this_grid();
    const int b = blockIdx.x, G = gridDim.x;

    for (int j = b; j < 64; j += G)
        do_cast(j, smem, w_value, w_off, w_attn, w_out, wvT, catT, wuT);
    __threadfence(); grid.sync();

    for (int j = b; j < NJF; j += G)
        do_front(j, smem, input_flatten, query, wvT, catT,
                 b_value, b_off, b_attn, valueH, proj);
    __threadfence(); grid.sync();

    for (int j = b; j < NJS; j += G)
        do_sample(j, smem, valueH, proj, refpts, oatH);
    __threadfence(); grid.sync();

    for (int j = b; j < NJO; j += G)
        do_out(j, smem, oatH, wuT, b_out, out);
}

// -------------------------------------------- fallback single-phase kernels
__global__ __launch_bounds__(256) void k_cast(
    const float* wv, const float* wo, const float* wa, const float* wu,
    _Float16* wvT, _Float16* catT, _Float16* wuT)
{
    __shared__ __align__(16) char smem[16640];
    do_cast(blockIdx.x, smem, wv, wo, wa, wu, wvT, catT, wuT);
}
__global__ __launch_bounds__(256) void k_front(
    const float* Aval, const float* query, const _Float16* wvT,
    const _Float16* catT, const float* bval, const float* boff,
    const float* batt, _Float16* valueH, _Float16* proj)
{
    __shared__ __align__(16) char smem[25600];
    do_front(blockIdx.x, smem, Aval, query, wvT, catT, bval, boff, batt,
             valueH, proj);
}
__global__ __launch_bounds__(256) void k_sample(
    const _Float16* value, const _Float16* proj, const float* refpts,
    _Float16* oat)
{
    __shared__ __align__(16) char smem[SMEM_MAX];
    do_sample(blockIdx.x, smem, value, proj, refpts, oat);
}
__global__ __launch_bounds__(256) void k_out(
    const _Float16* A, const _Float16* BT, const float* bias, float* C)
{
    __shared__ __align__(16) char smem[15360];
    do_out(blockIdx.x, smem, A, BT, bias, C);
}

extern "C" void kernel_launch(void* const* d_in, const int* in_sizes, int n_in,
                              void* d_out, int out_size, void* d_ws, size_t ws_size,
                              hipStream_t stream) {
    const float* query         = (const float*)d_in[0];
    const float* refpts        = (const float*)d_in[1];
    const float* input_flatten = (const float*)d_in[2];
    const float* w_value       = (const float*)d_in[3];
    const float* b_value       = (const float*)d_in[4];
    const float* w_off         = (const float*)d_in[5];
    const float* b_off         = (const float*)d_in[6];
    const float* w_attn        = (const float*)d_in[7];
    const float* b_attn        = (const float*)d_in[8];
    const float* w_out         = (const float*)d_in[9];
    const float* b_out         = (const float*)d_in[10];

    _Float16* valueH = (_Float16*)d_ws;                    // head-major [h][cell][32]
    _Float16* wvT    = valueH + (size_t)LENIN * DMODEL;
    _Float16* catT   = wvT + 256 * 256;
    _Float16* wuT    = catT + 512 * 256;
    _Float16* proj   = wuT + 256 * 256;                    // f16 [NQ][512]
    _Float16* oatH   = proj + (size_t)NQ * NPROJ;
    float*    outp   = (float*)d_out;

    // ---- try cooperative single-kernel launch
    int dev = 0;
    hipGetDevice(&dev);
    hipDeviceProp_t prop;
    hipGetDeviceProperties(&prop, dev);
    int maxb = 0;
    if (hipOccupancyMaxActiveBlocksPerMultiprocessor(
            &maxb, (const void*)mega, 256, 0) != hipSuccess || maxb <= 0)
        maxb = 0;
    int G = maxb * prop.multiProcessorCount;
    if (G > 512) G = 512;

    hipError_t cerr = hipErrorUnknown;
    if (G >= 64) {
        void* args[] = {
            (void*)&query, (void*)&refpts, (void*)&input_flatten,
            (void*)&w_value, (void*)&b_value, (void*)&w_off, (void*)&b_off,
            (void*)&w_attn, (void*)&b_attn, (void*)&w_out, (void*)&b_out,
            (void*)&valueH, (void*)&wvT, (void*)&catT, (void*)&wuT,
            (void*)&proj, (void*)&oatH, (void*)&outp };
        cerr = hipLaunchCooperativeKernel((const void*)mega, dim3(G), dim3(256),
                                          args, 0, stream);
    }
    if (cerr != hipSuccess) {
        // ---- fallback: 4-kernel pipeline (round-10 structure)
        k_cast<<<64, 256, 0, stream>>>(w_value, w_off, w_attn, w_out,
                                       wvT, catT, wuT);
        k_front<<<NJF, 256, 0, stream>>>(input_flatten, query, wvT, catT,
                                         b_value, b_off, b_attn, valueH, proj);
        k_sample<<<NJS, 256, 0, stream>>>(valueH, proj, refpts, oatH);
        k_out<<<NJO, 256, 0, stream>>>(oatH, wuT, b_out, outp);
    }
}

// Round 12
// 70.206 us; speedup vs baseline: 1.1780x; 1.1780x over previous
//
#include <hip/hip_runtime.h>
#include <hip/hip_bf16.h>

#define NQ     4000
#define DMODEL 256
#define NHEAD  8
#define NLVL   4
#define NPT    4
#define DHEAD  32
#define LENIN  37440
#define NOFF   384
#define NATT   128
#define NPROJ  512   // NOFF + NATT

#define NVBLK  (LENIN / 64)            // 585 value-role blocks
#define NQBLK  ((NQ + 63) / 64)        // 63 row tiles for query-side GEMMs
#define LDH    40                      // padded LDS row (halfs) for GEMM tiles
#define LDSW   132                     // padded LDS row (halfs) for C bounce

typedef _Float16 f16x8 __attribute__((ext_vector_type(8)));
typedef _Float16 f16x4 __attribute__((ext_vector_type(4)));
typedef float    f32x4 __attribute__((ext_vector_type(4)));

// ------------------------------------- all weight casts+transposes, 1 launch
__global__ __launch_bounds__(256) void cast_transpose_all(
    const float* __restrict__ wv, const float* __restrict__ wo,
    const float* __restrict__ wa, const float* __restrict__ wu,
    _Float16* __restrict__ wvT, _Float16* __restrict__ catT,
    _Float16* __restrict__ wuT)
{
    __shared__ float t[64][65];
    const int xt = blockIdx.x, kt = blockIdx.y;
    const float* W; _Float16* WT; int ncols, col0, nbase;
    if (xt < 4)       { W = wv; WT = wvT;  ncols = 256; col0 = xt * 64;        nbase = col0; }
    else if (xt < 10) { W = wo; WT = catT; ncols = 384; col0 = (xt - 4) * 64;  nbase = col0; }
    else if (xt < 12) { W = wa; WT = catT; ncols = 128; col0 = (xt - 10) * 64; nbase = 384 + col0; }
    else              { W = wu; WT = wuT;  ncols = 256; col0 = (xt - 12) * 64; nbase = col0; }

    const int by = kt * 64;           // k-range
    const int tid = threadIdx.x;
    const int c = tid & 63, r0 = tid >> 6;
    #pragma unroll
    for (int i = 0; i < 16; ++i) {
        int r = r0 + i * 4;
        t[r][c] = W[(size_t)(by + r) * ncols + col0 + c];
    }
    __syncthreads();
    #pragma unroll
    for (int i = 0; i < 16; ++i) {
        int n = r0 + i * 4;
        WT[(size_t)(nbase + n) * DMODEL + by + c] = (_Float16)t[c][n];
    }
}

// -------------------------------------------- merged front GEMM (fp32 input)
__global__ __launch_bounds__(256) void gemm_front(
    const float* __restrict__ Aval, const float* __restrict__ query,
    const _Float16* __restrict__ wvT, const _Float16* __restrict__ catT,
    const float* __restrict__ bval, const float* __restrict__ boff,
    const float* __restrict__ batt,
    _Float16* __restrict__ valueH, _Float16* __restrict__ proj)
{
    __shared__ __align__(16) char smem[25600];
    _Float16 (*As)[LDH] = (_Float16 (*)[LDH])smem;                 // 64 x 40
    _Float16 (*Bs)[LDH] = (_Float16 (*)[LDH])(smem + 64 * LDH * 2);// 256 x 40

    const int tid  = threadIdx.x;
    const int wave = tid >> 6, lane = tid & 63;
    const int l15 = lane & 15, l16 = lane >> 4;

    const int  bid   = blockIdx.x;
    const bool isval = (bid < NVBLK);
    const float* A; const _Float16* BT; int brow, ncb, M;
    if (isval) { A = Aval;  BT = wvT;  brow = bid * 64;  ncb = 0;  M = LENIN; }
    else       { int idx = bid - NVBLK; A = query; BT = catT;
                 brow = (idx >> 1) * 64; ncb = (idx & 1) * 256; M = NQ; }

    const int arow = tid >> 2, akq = (tid & 3) * 8;
    int arg = brow + arow; if (arg >= M) arg = M - 1;
    const float* aptr = A + (size_t)arg * DMODEL + akq;

    const _Float16* bptr[4];
    int bn[4], bkc[4];
    #pragma unroll
    for (int j = 0; j < 4; ++j) {
        int id = tid + 256 * j;            // chunk id = n*4 + kc
        bn[j] = id >> 2; bkc[j] = (id & 3) * 8;
        bptr[j] = BT + (size_t)(ncb + bn[j]) * DMODEL + bkc[j];
    }

    f32x4 acc[4][4] = {};   // [mi][ni]
    float4 a0, a1;
    f16x8 bh[4];

    a0 = *(const float4*)(const void*)aptr;
    a1 = *(const float4*)(const void*)(aptr + 4);
    #pragma unroll
    for (int j = 0; j < 4; ++j) bh[j] = *(const f16x8*)bptr[j];

    for (int k0 = 0; k0 < DMODEL; k0 += 32) {
        {
            f16x8 h;
            h[0] = (_Float16)a0.x; h[1] = (_Float16)a0.y;
            h[2] = (_Float16)a0.z; h[3] = (_Float16)a0.w;
            h[4] = (_Float16)a1.x; h[5] = (_Float16)a1.y;
            h[6] = (_Float16)a1.z; h[7] = (_Float16)a1.w;
            *(f16x8*)&As[arow][akq] = h;
        }
        #pragma unroll
        for (int j = 0; j < 4; ++j) *(f16x8*)&Bs[bn[j]][bkc[j]] = bh[j];
        __syncthreads();

        if (k0 + 32 < DMODEL) {   // issue next K-step's loads before MFMA
            a0 = *(const float4*)(const void*)(aptr + k0 + 32);
            a1 = *(const float4*)(const void*)(aptr + k0 + 36);
            #pragma unroll
            for (int j = 0; j < 4; ++j) bh[j] = *(const f16x8*)(bptr[j] + k0 + 32);
        }

        f16x8 af[4], bf[4];
        #pragma unroll
        for (int mi = 0; mi < 4; ++mi)
            af[mi] = *(const f16x8*)&As[mi * 16 + l15][l16 * 8];
        #pragma unroll
        for (int ni = 0; ni < 4; ++ni)
            bf[ni] = *(const f16x8*)&Bs[wave * 64 + ni * 16 + l15][l16 * 8];
        #pragma unroll
        for (int mi = 0; mi < 4; ++mi)
            #pragma unroll
            for (int ni = 0; ni < 4; ++ni)
                acc[mi][ni] = __builtin_amdgcn_mfma_f32_16x16x32_f16(
                    af[mi], bf[ni], acc[mi][ni], 0, 0, 0);
        __syncthreads();
    }

    if (isval) {
        // ---- epilogue A: LDS bounce -> coalesced head-major stores
        _Float16 (*out_s)[LDSW] = (_Float16 (*)[LDSW])smem;
        const int cell = tid >> 2, dchunk = tid & 3;
        #pragma unroll
        for (int hh = 0; hh < 2; ++hh) {
            if ((wave >> 1) == hh) {
                int cb = (wave & 1) * 64;
                #pragma unroll
                for (int ni = 0; ni < 4; ++ni) {
                    int col = wave * 64 + ni * 16 + l15;
                    float b = bval[col];
                    #pragma unroll
                    for (int mi = 0; mi < 4; ++mi)
                        #pragma unroll
                        for (int j = 0; j < 4; ++j)
                            out_s[mi * 16 + l16 * 4 + j][cb + ni * 16 + l15] =
                                (_Float16)(acc[mi][ni][j] + b);
                }
            }
            __syncthreads();
            #pragma unroll
            for (int h2 = 0; h2 < 4; ++h2) {
                int h = hh * 4 + h2;
                f16x4 lo = *(const f16x4*)&out_s[cell][h2 * 32 + dchunk * 8];
                f16x4 hi = *(const f16x4*)&out_s[cell][h2 * 32 + dchunk * 8 + 4];
                size_t base = ((size_t)h * LENIN + brow + cell) * DHEAD + dchunk * 8;
                *(f16x4*)&valueH[base]     = lo;
                *(f16x4*)&valueH[base + 4] = hi;
            }
            __syncthreads();
        }
    } else {
        // ---- epilogue B: f16 stores to proj
        #pragma unroll
        for (int ni = 0; ni < 4; ++ni) {
            int col = ncb + wave * 64 + ni * 16 + l15;
            float b = (col < NOFF) ? boff[col] : batt[col - NOFF];
            #pragma unroll
            for (int mi = 0; mi < 4; ++mi)
                #pragma unroll
                for (int j = 0; j < 4; ++j) {
                    int row = brow + mi * 16 + l16 * 4 + j;
                    if (row < NQ)
                        proj[(size_t)row * NPROJ + col] = (_Float16)(acc[mi][ni][j] + b);
                }
        }
    }
}

// --------------- sampler v5: ONE HEAD PER BLOCK (XCD-local value working set)
// grid = 1000 blocks: head = bid & 7 (round-robin -> same XCD per head),
// qg = bid >> 3. Each wave handles 8 queries of that head.
// Per-head value slice = 2.4 MB < 4 MB per-XCD L2.
// Corner table: packed uint = cell_idx (low 16) | f16 weight bits (high 16).
__global__ __launch_bounds__(256) void sample_fused5(
    const _Float16* __restrict__ value, const _Float16* __restrict__ proj,
    const float* __restrict__ refpts, _Float16* __restrict__ oat)
{
    __shared__ float    loc_s[4][8][48];     //  6144 B
    __shared__ float    aw_s [4][8][16];     //  2048 B
    __shared__ unsigned cp_s [4][8][192];    // 24576 B   [pt*12 + c], c<8
    // total 32768 B -> 4 blocks/CU

    const int tid  = threadIdx.x;
    const int wv   = tid >> 6, lane = tid & 63;
    const int head = blockIdx.x & 7;
    const int qg   = blockIdx.x >> 3;
    const int q0   = qg * 32 + wv * 8;

    // ---- phase 0: per-query loc (lanes 0-47) + softmax (lanes 48-63)
    #pragma unroll
    for (int i = 0; i < 8; ++i) {
        const int q = q0 + i;
        if (lane < 48) {
            float v = (float)proj[(size_t)q * NPROJ + head * 48 + lane];
            int pt = lane / 3, c = lane - pt * 3, lvl = pt >> 2;
            float norm = (float)(32 >> lvl);
            loc_s[wv][i][lane] =
                refpts[((size_t)q * NLVL + lvl) * 3 + c] + v / norm;
        } else {
            int j = lane - 48;
            float v = (float)proj[(size_t)q * NPROJ + NOFF + head * 16 + j];
            float m = v;
            #pragma unroll
            for (int o = 8; o >= 1; o >>= 1) m = fmaxf(m, __shfl_xor(m, o, 16));
            float e = expf(v - m);
            float s = e;
            #pragma unroll
            for (int o = 8; o >= 1; o >>= 1) s += __shfl_xor(s, o, 16);
            aw_s[wv][i][j] = e / s;
        }
    }
    __syncthreads();

    // ---- phase 1: 8q x 16pt x 8corners = 1024 per wave; 16 per lane
    #pragma unroll
    for (int k = 0; k < 16; ++k) {
        int id = k * 64 + lane;            // i(3b) | pt(4b) | c(3b)
        int i = id >> 7, pt = (id >> 3) & 15, c = id & 7;
        int lvl = pt >> 2;
        int S = 32 >> lvl;
        float Sf = (float)S;
        int base = (lvl == 0) ? 0 : (lvl == 1) ? 32768 : (lvl == 2) ? 36864 : 37376;

        float lx = loc_s[wv][i][pt * 3 + 0];
        float ly = loc_s[wv][i][pt * 3 + 1];
        float lz = loc_s[wv][i][pt * 3 + 2];
        float aw = aw_s[wv][i][pt];

        float x = lx * Sf - 0.5f, y = ly * Sf - 0.5f, z = lz * Sf - 0.5f;
        float x0f = floorf(x), y0f = floorf(y), z0f = floorf(z);
        float fx = x - x0f, fy = y - y0f, fz = z - z0f;
        int dx = c & 1, dy = (c >> 1) & 1, dz = c >> 2;
        int xi = (int)x0f + dx, yi = (int)y0f + dy, zi = (int)z0f + dz;
        float wx = dx ? fx : 1.f - fx;
        float wy = dy ? fy : 1.f - fy;
        float wz = dz ? fz : 1.f - fz;
        bool valid = (unsigned)xi < (unsigned)S &&
                     (unsigned)yi < (unsigned)S &&
                     (unsigned)zi < (unsigned)S;
        int idx = (zi * S + yi) * S + xi;        // only meaningful if valid
        unsigned cell = valid ? (unsigned)(base + idx) : 0u;
        float w = valid ? wx * wy * wz * aw : 0.f;
        unsigned short wb = __builtin_bit_cast(unsigned short, (_Float16)w);
        cp_s[wv][i][pt * 12 + c] = cell | ((unsigned)wb << 16);
    }
    __syncthreads();

    // ---- phase 2: gather. lane = pt(4b)|chunk(2b); 8 corners serial/lane;
    //      pt-reduction via 4 shfl_xor rounds (lane bits 2..5).
    const int pt = lane >> 2, chunk = lane & 3;
    const char* vb = (const char*)(value + (size_t)head * LENIN * DHEAD) + chunk * 16;

    #pragma unroll
    for (int i = 0; i < 8; ++i) {
        const unsigned* cp = &cp_s[wv][i][pt * 12];
        uint4 p0 = *(const uint4*)&cp[0];
        uint4 p1 = *(const uint4*)&cp[4];

        float acc[8] = {};
        unsigned pk[8] = {p0.x, p0.y, p0.z, p0.w, p1.x, p1.y, p1.z, p1.w};
        #pragma unroll
        for (int c = 0; c < 8; ++c) {
            unsigned p = pk[c];
            float w = (float)__builtin_bit_cast(_Float16, (unsigned short)(p >> 16));
            f16x8 v = *(const f16x8*)(vb + (size_t)(p & 0xFFFFu) * 64u);
            #pragma unroll
            for (int j = 0; j < 8; ++j) acc[j] += w * (float)v[j];
        }
        // reduce across the 16 pts (lane bits 2..5)
        #pragma unroll
        for (int o = 4; o <= 32; o <<= 1)
            #pragma unroll
            for (int j = 0; j < 8; ++j) acc[j] += __shfl_xor(acc[j], o);

        if (pt == 0) {
            f16x8 r;
            #pragma unroll
            for (int j = 0; j < 8; ++j) r[j] = (_Float16)acc[j];
            *(f16x8*)&oat[(size_t)(q0 + i) * DMODEL + head * DHEAD + chunk * 8] = r;
        }
    }
}

// ---------------------- output projection (f16 in, MFMA, 64x128 per block)
__global__ __launch_bounds__(256) void gemm_out(
    const _Float16* __restrict__ A, const _Float16* __restrict__ BT,
    const float* __restrict__ bias, float* __restrict__ C)
{
    __shared__ __align__(16) _Float16 As[64][LDH];
    __shared__ __align__(16) _Float16 Bs[128][LDH];
    const int tid  = threadIdx.x;
    const int wave = tid >> 6, lane = tid & 63;
    const int brow = blockIdx.x * 64;
    const int bcol = blockIdx.y * 128;
    const int l15 = lane & 15, l16 = lane >> 4;

    const int arow = tid >> 2, akq = (tid & 3) * 8;
    int arg = brow + arow; if (arg >= NQ) arg = NQ - 1;
    const _Float16* aptr = A + (size_t)arg * DMODEL + akq;

    const _Float16* bptr[2];
    int bn[2], bkc[2];
    #pragma unroll
    for (int j = 0; j < 2; ++j) {
        int id = tid + 256 * j;
        bn[j] = id >> 2; bkc[j] = (id & 3) * 8;
        bptr[j] = BT + (size_t)(bcol + bn[j]) * DMODEL + bkc[j];
    }

    f32x4 acc[4][2] = {};
    f16x8 ah, bh[2];
    ah = *(const f16x8*)(const void*)aptr;
    #pragma unroll
    for (int j = 0; j < 2; ++j) bh[j] = *(const f16x8*)bptr[j];

    for (int k0 = 0; k0 < DMODEL; k0 += 32) {
        *(f16x8*)&As[arow][akq] = ah;
        #pragma unroll
        for (int j = 0; j < 2; ++j) *(f16x8*)&Bs[bn[j]][bkc[j]] = bh[j];
        __syncthreads();

        if (k0 + 32 < DMODEL) {
            ah = *(const f16x8*)(const void*)(aptr + k0 + 32);
            #pragma unroll
            for (int j = 0; j < 2; ++j) bh[j] = *(const f16x8*)(bptr[j] + k0 + 32);
        }

        f16x8 af[4], bf[2];
        #pragma unroll
        for (int mi = 0; mi < 4; ++mi)
            af[mi] = *(const f16x8*)&As[mi * 16 + l15][l16 * 8];
        #pragma unroll
        for (int ni = 0; ni < 2; ++ni)
            bf[ni] = *(const f16x8*)&Bs[wave * 32 + ni * 16 + l15][l16 * 8];
        #pragma unroll
        for (int mi = 0; mi < 4; ++mi)
            #pragma unroll
            for (int ni = 0; ni < 2; ++ni)
                acc[mi][ni] = __builtin_amdgcn_mfma_f32_16x16x32_f16(
                    af[mi], bf[ni], acc[mi][ni], 0, 0, 0);
        __syncthreads();
    }

    #pragma unroll
    for (int ni = 0; ni < 2; ++ni) {
        int col = bcol + wave * 32 + ni * 16 + l15;
        float b = bias[col];
        #pragma unroll
        for (int mi = 0; mi < 4; ++mi)
            #pragma unroll
            for (int j = 0; j < 4; ++j) {
                int row = brow + mi * 16 + l16 * 4 + j;
                if (row < NQ)
                    C[(size_t)row * DMODEL + col] = acc[mi][ni][j] + b;
            }
    }
}

extern "C" void kernel_launch(void* const* d_in, const int* in_sizes, int n_in,
                              void* d_out, int out_size, void* d_ws, size_t ws_size,
                              hipStream_t stream) {
    const float* query         = (const float*)d_in[0];
    const float* refpts        = (const float*)d_in[1];
    const float* input_flatten = (const float*)d_in[2];
    const float* w_value       = (const float*)d_in[3];
    const float* b_value       = (const float*)d_in[4];
    const float* w_off         = (const float*)d_in[5];
    const float* b_off         = (const float*)d_in[6];
    const float* w_attn        = (const float*)d_in[7];
    const float* b_attn        = (const float*)d_in[8];
    const float* w_out         = (const float*)d_in[9];
    const float* b_out         = (const float*)d_in[10];

    _Float16* valueH = (_Float16*)d_ws;                    // head-major [h][cell][32]
    _Float16* wvT    = valueH + (size_t)LENIN * DMODEL;
    _Float16* catT   = wvT + 256 * 256;
    _Float16* wuT    = catT + 512 * 256;
    _Float16* proj   = wuT + 256 * 256;                    // f16 [NQ][512]
    _Float16* oatH   = proj + (size_t)NQ * NPROJ;
    // total ~26 MB of workspace

    cast_transpose_all<<<dim3(16, 4), 256, 0, stream>>>(
        w_value, w_off, w_attn, w_out, wvT, catT, wuT);

    gemm_front<<<NVBLK + NQBLK * 2, 256, 0, stream>>>(
        input_flatten, query, wvT, catT, b_value, b_off, b_attn, valueH, proj);

    sample_fused5<<<1000, 256, 0, stream>>>(valueH, proj, refpts, oatH);

    gemm_out<<<dim3(NQBLK, 2), 256, 0, stream>>>(oatH, wuT, b_out, (float*)d_out);
}

// Round 13
// 61.162 us; speedup vs baseline: 1.3522x; 1.1479x over previous
//
#include <hip/hip_runtime.h>
#include <hip/hip_bf16.h>

#define NQ     4000
#define DMODEL 256
#define NHEAD  8
#define NLVL   4
#define NPT    4
#define DHEAD  32
#define LENIN  37440
#define NOFF   384
#define NATT   128
#define NPROJ  512   // NOFF + NATT

#define NVBLK  (LENIN / 64)            // 585 value-role blocks
#define NQBLK  ((NQ + 63) / 64)        // 63 row tiles for query-side GEMMs
#define LDH    40                      // padded LDS row (halfs) for GEMM tiles
#define LDSW   132                     // padded LDS row (halfs) for C bounce
#define CTB    132                     // padded corner-table stride (entries)

typedef _Float16 f16x8 __attribute__((ext_vector_type(8)));
typedef _Float16 f16x4 __attribute__((ext_vector_type(4)));
typedef float    f32x4 __attribute__((ext_vector_type(4)));

// ------------------------------------- all weight casts+transposes, 1 launch
__global__ __launch_bounds__(256) void cast_transpose_all(
    const float* __restrict__ wv, const float* __restrict__ wo,
    const float* __restrict__ wa, const float* __restrict__ wu,
    _Float16* __restrict__ wvT, _Float16* __restrict__ catT,
    _Float16* __restrict__ wuT)
{
    __shared__ float t[64][65];
    const int xt = blockIdx.x, kt = blockIdx.y;
    const float* W; _Float16* WT; int ncols, col0, nbase;
    if (xt < 4)       { W = wv; WT = wvT;  ncols = 256; col0 = xt * 64;        nbase = col0; }
    else if (xt < 10) { W = wo; WT = catT; ncols = 384; col0 = (xt - 4) * 64;  nbase = col0; }
    else if (xt < 12) { W = wa; WT = catT; ncols = 128; col0 = (xt - 10) * 64; nbase = 384 + col0; }
    else              { W = wu; WT = wuT;  ncols = 256; col0 = (xt - 12) * 64; nbase = col0; }

    const int by = kt * 64;           // k-range
    const int tid = threadIdx.x;
    const int c = tid & 63, r0 = tid >> 6;
    #pragma unroll
    for (int i = 0; i < 16; ++i) {
        int r = r0 + i * 4;
        t[r][c] = W[(size_t)(by + r) * ncols + col0 + c];
    }
    __syncthreads();
    #pragma unroll
    for (int i = 0; i < 16; ++i) {
        int n = r0 + i * 4;
        WT[(size_t)(nbase + n) * DMODEL + by + c] = (_Float16)t[c][n];
    }
}

// -------------------------------------------- merged front GEMM (fp32 input)
__global__ __launch_bounds__(256) void gemm_front(
    const float* __restrict__ Aval, const float* __restrict__ query,
    const _Float16* __restrict__ wvT, const _Float16* __restrict__ catT,
    const float* __restrict__ bval, const float* __restrict__ boff,
    const float* __restrict__ batt,
    _Float16* __restrict__ valueH, _Float16* __restrict__ proj)
{
    __shared__ __align__(16) char smem[25600];
    _Float16 (*As)[LDH] = (_Float16 (*)[LDH])smem;                 // 64 x 40
    _Float16 (*Bs)[LDH] = (_Float16 (*)[LDH])(smem + 64 * LDH * 2);// 256 x 40

    const int tid  = threadIdx.x;
    const int wave = tid >> 6, lane = tid & 63;
    const int l15 = lane & 15, l16 = lane >> 4;

    const int  bid   = blockIdx.x;
    const bool isval = (bid < NVBLK);
    const float* A; const _Float16* BT; int brow, ncb, M;
    if (isval) { A = Aval;  BT = wvT;  brow = bid * 64;  ncb = 0;  M = LENIN; }
    else       { int idx = bid - NVBLK; A = query; BT = catT;
                 brow = (idx >> 1) * 64; ncb = (idx & 1) * 256; M = NQ; }

    const int arow = tid >> 2, akq = (tid & 3) * 8;
    int arg = brow + arow; if (arg >= M) arg = M - 1;
    const float* aptr = A + (size_t)arg * DMODEL + akq;

    const _Float16* bptr[4];
    int bn[4], bkc[4];
    #pragma unroll
    for (int j = 0; j < 4; ++j) {
        int id = tid + 256 * j;            // chunk id = n*4 + kc
        bn[j] = id >> 2; bkc[j] = (id & 3) * 8;
        bptr[j] = BT + (size_t)(ncb + bn[j]) * DMODEL + bkc[j];
    }

    f32x4 acc[4][4] = {};   // [mi][ni]
    float4 a0, a1;
    f16x8 bh[4];

    a0 = *(const float4*)(const void*)aptr;
    a1 = *(const float4*)(const void*)(aptr + 4);
    #pragma unroll
    for (int j = 0; j < 4; ++j) bh[j] = *(const f16x8*)bptr[j];

    for (int k0 = 0; k0 < DMODEL; k0 += 32) {
        {
            f16x8 h;
            h[0] = (_Float16)a0.x; h[1] = (_Float16)a0.y;
            h[2] = (_Float16)a0.z; h[3] = (_Float16)a0.w;
            h[4] = (_Float16)a1.x; h[5] = (_Float16)a1.y;
            h[6] = (_Float16)a1.z; h[7] = (_Float16)a1.w;
            *(f16x8*)&As[arow][akq] = h;
        }
        #pragma unroll
        for (int j = 0; j < 4; ++j) *(f16x8*)&Bs[bn[j]][bkc[j]] = bh[j];
        __syncthreads();

        if (k0 + 32 < DMODEL) {   // issue next K-step's loads before MFMA
            a0 = *(const float4*)(const void*)(aptr + k0 + 32);
            a1 = *(const float4*)(const void*)(aptr + k0 + 36);
            #pragma unroll
            for (int j = 0; j < 4; ++j) bh[j] = *(const f16x8*)(bptr[j] + k0 + 32);
        }

        f16x8 af[4], bf[4];
        #pragma unroll
        for (int mi = 0; mi < 4; ++mi)
            af[mi] = *(const f16x8*)&As[mi * 16 + l15][l16 * 8];
        #pragma unroll
        for (int ni = 0; ni < 4; ++ni)
            bf[ni] = *(const f16x8*)&Bs[wave * 64 + ni * 16 + l15][l16 * 8];
        #pragma unroll
        for (int mi = 0; mi < 4; ++mi)
            #pragma unroll
            for (int ni = 0; ni < 4; ++ni)
                acc[mi][ni] = __builtin_amdgcn_mfma_f32_16x16x32_f16(
                    af[mi], bf[ni], acc[mi][ni], 0, 0, 0);
        __syncthreads();
    }

    if (isval) {
        // ---- epilogue A: LDS bounce -> coalesced head-major stores
        _Float16 (*out_s)[LDSW] = (_Float16 (*)[LDSW])smem;
        const int cell = tid >> 2, dchunk = tid & 3;
        #pragma unroll
        for (int hh = 0; hh < 2; ++hh) {
            if ((wave >> 1) == hh) {
                int cb = (wave & 1) * 64;
                #pragma unroll
                for (int ni = 0; ni < 4; ++ni) {
                    int col = wave * 64 + ni * 16 + l15;
                    float b = bval[col];
                    #pragma unroll
                    for (int mi = 0; mi < 4; ++mi)
                        #pragma unroll
                        for (int j = 0; j < 4; ++j)
                            out_s[mi * 16 + l16 * 4 + j][cb + ni * 16 + l15] =
                                (_Float16)(acc[mi][ni][j] + b);
                }
            }
            __syncthreads();
            #pragma unroll
            for (int h2 = 0; h2 < 4; ++h2) {
                int h = hh * 4 + h2;
                f16x4 lo = *(const f16x4*)&out_s[cell][h2 * 32 + dchunk * 8];
                f16x4 hi = *(const f16x4*)&out_s[cell][h2 * 32 + dchunk * 8 + 4];
                size_t base = ((size_t)h * LENIN + brow + cell) * DHEAD + dchunk * 8;
                *(f16x4*)&valueH[base]     = lo;
                *(f16x4*)&valueH[base + 4] = hi;
            }
            __syncthreads();
        }
    } else {
        // ---- epilogue B: f16 stores to proj
        #pragma unroll
        for (int ni = 0; ni < 4; ++ni) {
            int col = ncb + wave * 64 + ni * 16 + l15;
            float b = (col < NOFF) ? boff[col] : batt[col - NOFF];
            #pragma unroll
            for (int mi = 0; mi < 4; ++mi)
                #pragma unroll
                for (int j = 0; j < 4; ++j) {
                    int row = brow + mi * 16 + l16 * 4 + j;
                    if (row < NQ)
                        proj[(size_t)row * NPROJ + col] = (_Float16)(acc[mi][ni][j] + b);
                }
        }
    }
}

// -------- sampler v6: v4 gather structure + head-pair XCD-local partitioning
// grid = 250 query-groups x 4 head-pairs; hp = bid & 3 -> with round-robin
// block->XCD dispatch (XCD = bid & 7), each XCD serves ONE head-pair
// (working set 4.8 MB ~ per-XCD L2). Block: 16 queries x 2 heads.
// Lane = q2(2b) | h1(1b) | s(3b); per-lane work identical to v4.
__global__ __launch_bounds__(256) void sample_fused6(
    const _Float16* __restrict__ value, const _Float16* __restrict__ proj,
    const float* __restrict__ refpts, _Float16* __restrict__ oat)
{
    __shared__ float    loc_s[16][2][48];        //  6144 B
    __shared__ float    aw_s [16][2][16];        //  2048 B
    __shared__ unsigned ca_s [32 * CTB];         // 16896 B  table g=lq*2+h1
    __shared__ _Float16 cw_s [32 * CTB];         //  8448 B
    // total 33536 B -> 4 blocks/CU

    const int tid  = threadIdx.x;
    const int wv   = tid >> 6, lane = tid & 63;
    const int hp   = blockIdx.x & 3;            // head pair -> XCD-stable
    const int q0   = (blockIdx.x >> 2) * 16;

    // ---- phase 0a: locations (16q x 2h x 48 = 1536 jobs)
    #pragma unroll
    for (int it = 0; it < 6; ++it) {
        int id = it * 256 + tid;
        int lq = id / 96, r = id - lq * 96;
        int h1 = r / 48,  c = r - h1 * 48;
        int pt = c / 3,   ax = c - pt * 3, lvl = pt >> 2;
        int head = hp * 2 + h1;
        int q = q0 + lq;
        float v = (float)proj[(size_t)q * NPROJ + head * 48 + c];
        float norm = (float)(32 >> lvl);
        loc_s[lq][h1][c] = refpts[((size_t)q * NLVL + lvl) * 3 + ax] + v / norm;
    }
    // ---- phase 0b: softmax (16q x 2h x 16 = 512 jobs, 16-lane groups)
    #pragma unroll
    for (int it = 0; it < 2; ++it) {
        int id = it * 256 + tid;
        int lq = id >> 5, h1 = (id >> 4) & 1, j = id & 15;
        int head = hp * 2 + h1;
        int q = q0 + lq;
        float v = (float)proj[(size_t)q * NPROJ + NOFF + head * 16 + j];
        float m = v;
        #pragma unroll
        for (int o = 8; o >= 1; o >>= 1) m = fmaxf(m, __shfl_xor(m, o, 16));
        float e = expf(v - m);
        float s = e;
        #pragma unroll
        for (int o = 8; o >= 1; o >>= 1) s += __shfl_xor(s, o, 16);
        aw_s[lq][h1][j] = e / s;
    }
    __syncthreads();

    // ---- phase 1: corner table (16 iters; iter k = local query k)
    #pragma unroll
    for (int k = 0; k < 16; ++k) {
        const int lq = k;
        int h1 = tid >> 7, pt = (tid >> 3) & 15, c = tid & 7;
        int lvl = pt >> 2;
        int S = 32 >> lvl;
        float Sf = (float)S;
        int base = (lvl == 0) ? 0 : (lvl == 1) ? 32768 : (lvl == 2) ? 36864 : 37376;

        float lx = loc_s[lq][h1][pt * 3 + 0];
        float ly = loc_s[lq][h1][pt * 3 + 1];
        float lz = loc_s[lq][h1][pt * 3 + 2];
        float aw = aw_s[lq][h1][pt];

        float x = lx * Sf - 0.5f, y = ly * Sf - 0.5f, z = lz * Sf - 0.5f;
        float x0f = floorf(x), y0f = floorf(y), z0f = floorf(z);
        float fx = x - x0f, fy = y - y0f, fz = z - z0f;
        int dx = c & 1, dy = (c >> 1) & 1, dz = c >> 2;
        int xi = (int)x0f + dx, yi = (int)y0f + dy, zi = (int)z0f + dz;
        float wx = dx ? fx : 1.f - fx;
        float wy = dy ? fy : 1.f - fy;
        float wz = dz ? fz : 1.f - fz;
        bool valid = (unsigned)xi < (unsigned)S &&
                     (unsigned)yi < (unsigned)S &&
                     (unsigned)zi < (unsigned)S;
        int idx = (zi * S + yi) * S + xi;            // meaningful iff valid
        unsigned addr = valid ? (unsigned)(base + idx) * 64u : 0u;
        float w = valid ? wx * wy * wz * aw : 0.f;
        int g = lq * 2 + h1;
        ca_s[g * CTB + pt * 8 + c] = addr;
        cw_s[g * CTB + pt * 8 + c] = (_Float16)w;
    }
    __syncthreads();

    // ---- phase 2: gather (identical structure to v4; 64 x 16B loads/lane)
    const int q2 = (lane >> 4) & 3, h1 = (lane >> 3) & 1, s = lane & 7;
    const int chunk = s & 3, half4 = (s >> 2) * 4;
    const int lq = wv * 4 + q2, g = lq * 2 + h1;
    const int head = hp * 2 + h1;
    const char* vb = (const char*)(value + (size_t)head * LENIN * DHEAD) + chunk * 16;
    const unsigned* ca  = &ca_s[g * CTB];
    const _Float16* cwp = &cw_s[g * CTB];

    float acc[8] = {};
    #pragma unroll 4
    for (int pt = 0; pt < 16; ++pt) {
        uint4 a4 = *(const uint4*)&ca[pt * 8 + half4];
        f16x4 w4 = *(const f16x4*)&cwp[pt * 8 + half4];
        {
            f16x8 v = *(const f16x8*)(vb + a4.x); float w = (float)w4[0];
            #pragma unroll
            for (int j = 0; j < 8; ++j) acc[j] += w * (float)v[j];
        }
        {
            f16x8 v = *(const f16x8*)(vb + a4.y); float w = (float)w4[1];
            #pragma unroll
            for (int j = 0; j < 8; ++j) acc[j] += w * (float)v[j];
        }
        {
            f16x8 v = *(const f16x8*)(vb + a4.z); float w = (float)w4[2];
            #pragma unroll
            for (int j = 0; j < 8; ++j) acc[j] += w * (float)v[j];
        }
        {
            f16x8 v = *(const f16x8*)(vb + a4.w); float w = (float)w4[3];
            #pragma unroll
            for (int j = 0; j < 8; ++j) acc[j] += w * (float)v[j];
        }
    }
    // combine the two corner-halves (lanes s and s^4 own same channels)
    #pragma unroll
    for (int j = 0; j < 8; ++j) acc[j] += __shfl_xor(acc[j], 4);

    if (s < 4) {
        f16x8 r;
        #pragma unroll
        for (int j = 0; j < 8; ++j) r[j] = (_Float16)acc[j];
        *(f16x8*)&oat[(size_t)(q0 + lq) * DMODEL + head * DHEAD + chunk * 8] = r;
    }
}

// ---------------------- output projection (f16 in, MFMA, 64x128 per block)
__global__ __launch_bounds__(256) void gemm_out(
    const _Float16* __restrict__ A, const _Float16* __restrict__ BT,
    const float* __restrict__ bias, float* __restrict__ C)
{
    __shared__ __align__(16) _Float16 As[64][LDH];
    __shared__ __align__(16) _Float16 Bs[128][LDH];
    const int tid  = threadIdx.x;
    const int wave = tid >> 6, lane = tid & 63;
    const int brow = blockIdx.x * 64;
    const int bcol = blockIdx.y * 128;
    const int l15 = lane & 15, l16 = lane >> 4;

    const int arow = tid >> 2, akq = (tid & 3) * 8;
    int arg = brow + arow; if (arg >= NQ) arg = NQ - 1;
    const _Float16* aptr = A + (size_t)arg * DMODEL + akq;

    const _Float16* bptr[2];
    int bn[2], bkc[2];
    #pragma unroll
    for (int j = 0; j < 2; ++j) {
        int id = tid + 256 * j;
        bn[j] = id >> 2; bkc[j] = (id & 3) * 8;
        bptr[j] = BT + (size_t)(bcol + bn[j]) * DMODEL + bkc[j];
    }

    f32x4 acc[4][2] = {};
    f16x8 ah, bh[2];
    ah = *(const f16x8*)(const void*)aptr;
    #pragma unroll
    for (int j = 0; j < 2; ++j) bh[j] = *(const f16x8*)bptr[j];

    for (int k0 = 0; k0 < DMODEL; k0 += 32) {
        *(f16x8*)&As[arow][akq] = ah;
        #pragma unroll
        for (int j = 0; j < 2; ++j) *(f16x8*)&Bs[bn[j]][bkc[j]] = bh[j];
        __syncthreads();

        if (k0 + 32 < DMODEL) {
            ah = *(const f16x8*)(const void*)(aptr + k0 + 32);
            #pragma unroll
            for (int j = 0; j < 2; ++j) bh[j] = *(const f16x8*)(bptr[j] + k0 + 32);
        }

        f16x8 af[4], bf[2];
        #pragma unroll
        for (int mi = 0; mi < 4; ++mi)
            af[mi] = *(const f16x8*)&As[mi * 16 + l15][l16 * 8];
        #pragma unroll
        for (int ni = 0; ni < 2; ++ni)
            bf[ni] = *(const f16x8*)&Bs[wave * 32 + ni * 16 + l15][l16 * 8];
        #pragma unroll
        for (int mi = 0; mi < 4; ++mi)
            #pragma unroll
            for (int ni = 0; ni < 2; ++ni)
                acc[mi][ni] = __builtin_amdgcn_mfma_f32_16x16x32_f16(
                    af[mi], bf[ni], acc[mi][ni], 0, 0, 0);
        __syncthreads();
    }

    #pragma unroll
    for (int ni = 0; ni < 2; ++ni) {
        int col = bcol + wave * 32 + ni * 16 + l15;
        float b = bias[col];
        #pragma unroll
        for (int mi = 0; mi < 4; ++mi)
            #pragma unroll
            for (int j = 0; j < 4; ++j) {
                int row = brow + mi * 16 + l16 * 4 + j;
                if (row < NQ)
                    C[(size_t)row * DMODEL + col] = acc[mi][ni][j] + b;
            }
    }
}

extern "C" void kernel_launch(void* const* d_in, const int* in_sizes, int n_in,
                              void* d_out, int out_size, void* d_ws, size_t ws_size,
                              hipStream_t stream) {
    const float* query         = (const float*)d_in[0];
    const float* refpts        = (const float*)d_in[1];
    const float* input_flatten = (const float*)d_in[2];
    const float* w_value       = (const float*)d_in[3];
    const float* b_value       = (const float*)d_in[4];
    const float* w_off         = (const float*)d_in[5];
    const float* b_off         = (const float*)d_in[6];
    const float* w_attn        = (const float*)d_in[7];
    const float* b_attn        = (const float*)d_in[8];
    const float* w_out         = (const float*)d_in[9];
    const float* b_out         = (const float*)d_in[10];

    _Float16* valueH = (_Float16*)d_ws;                    // head-major [h][cell][32]
    _Float16* wvT    = valueH + (size_t)LENIN * DMODEL;
    _Float16* catT   = wvT + 256 * 256;
    _Float16* wuT    = catT + 512 * 256;
    _Float16* proj   = wuT + 256 * 256;                    // f16 [NQ][512]
    _Float16* oatH   = proj + (size_t)NQ * NPROJ;
    // total ~26 MB of workspace

    cast_transpose_all<<<dim3(16, 4), 256, 0, stream>>>(
        w_value, w_off, w_attn, w_out, wvT, catT, wuT);

    gemm_front<<<NVBLK + NQBLK * 2, 256, 0, stream>>>(
        input_flatten, query, wvT, catT, b_value, b_off, b_attn, valueH, proj);

    sample_fused6<<<1000, 256, 0, stream>>>(valueH, proj, refpts, oatH);

    gemm_out<<<dim3(NQBLK, 2), 256, 0, stream>>>(oatH, wuT, b_out, (float*)d_out);
}

// Round 14
// 60.353 us; speedup vs baseline: 1.3703x; 1.0134x over previous
//
#include <hip/hip_runtime.h>
#include <hip/hip_bf16.h>

#define NQ     4000
#define DMODEL 256
#define NHEAD  8
#define NLVL   4
#define NPT    4
#define DHEAD  32
#define LENIN  37440
#define NOFF   384
#define NATT   128
#define NPROJ  512   // NOFF + NATT

#define NVBLK  (LENIN / 64)            // 585 value-role blocks
#define NQBLK  ((NQ + 63) / 64)        // 63 row tiles for query-side GEMMs
#define LDH    40                      // padded LDS row (halfs) for GEMM tiles
#define LDSW   132                     // padded LDS row (halfs) for C bounce
#define CTB    132                     // padded corner-table stride (entries)

typedef _Float16 f16x8 __attribute__((ext_vector_type(8)));
typedef _Float16 f16x4 __attribute__((ext_vector_type(4)));
typedef float    f32x4 __attribute__((ext_vector_type(4)));

// ------------------------------------- all weight casts+transposes, 1 launch
__global__ __launch_bounds__(256) void cast_transpose_all(
    const float* __restrict__ wv, const float* __restrict__ wo,
    const float* __restrict__ wa, const float* __restrict__ wu,
    _Float16* __restrict__ wvT, _Float16* __restrict__ catT,
    _Float16* __restrict__ wuT)
{
    __shared__ float t[64][65];
    const int xt = blockIdx.x, kt = blockIdx.y;
    const float* W; _Float16* WT; int ncols, col0, nbase;
    if (xt < 4)       { W = wv; WT = wvT;  ncols = 256; col0 = xt * 64;        nbase = col0; }
    else if (xt < 10) { W = wo; WT = catT; ncols = 384; col0 = (xt - 4) * 64;  nbase = col0; }
    else if (xt < 12) { W = wa; WT = catT; ncols = 128; col0 = (xt - 10) * 64; nbase = 384 + col0; }
    else              { W = wu; WT = wuT;  ncols = 256; col0 = (xt - 12) * 64; nbase = col0; }

    const int by = kt * 64;           // k-range
    const int tid = threadIdx.x;
    const int c = tid & 63, r0 = tid >> 6;
    #pragma unroll
    for (int i = 0; i < 16; ++i) {
        int r = r0 + i * 4;
        t[r][c] = W[(size_t)(by + r) * ncols + col0 + c];
    }
    __syncthreads();
    #pragma unroll
    for (int i = 0; i < 16; ++i) {
        int n = r0 + i * 4;
        WT[(size_t)(nbase + n) * DMODEL + by + c] = (_Float16)t[c][n];
    }
}

// -------------------------------------------- merged front GEMM (fp32 input)
__global__ __launch_bounds__(256) void gemm_front(
    const float* __restrict__ Aval, const float* __restrict__ query,
    const _Float16* __restrict__ wvT, const _Float16* __restrict__ catT,
    const float* __restrict__ bval, const float* __restrict__ boff,
    const float* __restrict__ batt,
    _Float16* __restrict__ valueH, _Float16* __restrict__ proj)
{
    __shared__ __align__(16) char smem[25600];
    _Float16 (*As)[LDH] = (_Float16 (*)[LDH])smem;                 // 64 x 40
    _Float16 (*Bs)[LDH] = (_Float16 (*)[LDH])(smem + 64 * LDH * 2);// 256 x 40

    const int tid  = threadIdx.x;
    const int wave = tid >> 6, lane = tid & 63;
    const int l15 = lane & 15, l16 = lane >> 4;

    const int  bid   = blockIdx.x;
    const bool isval = (bid < NVBLK);
    const float* A; const _Float16* BT; int brow, ncb, M;
    if (isval) { A = Aval;  BT = wvT;  brow = bid * 64;  ncb = 0;  M = LENIN; }
    else       { int idx = bid - NVBLK; A = query; BT = catT;
                 brow = (idx >> 1) * 64; ncb = (idx & 1) * 256; M = NQ; }

    const int arow = tid >> 2, akq = (tid & 3) * 8;
    int arg = brow + arow; if (arg >= M) arg = M - 1;
    const float* aptr = A + (size_t)arg * DMODEL + akq;

    const _Float16* bptr[4];
    int bn[4], bkc[4];
    #pragma unroll
    for (int j = 0; j < 4; ++j) {
        int id = tid + 256 * j;            // chunk id = n*4 + kc
        bn[j] = id >> 2; bkc[j] = (id & 3) * 8;
        bptr[j] = BT + (size_t)(ncb + bn[j]) * DMODEL + bkc[j];
    }

    f32x4 acc[4][4] = {};   // [mi][ni]
    float4 a0, a1;
    f16x8 bh[4];

    a0 = *(const float4*)(const void*)aptr;
    a1 = *(const float4*)(const void*)(aptr + 4);
    #pragma unroll
    for (int j = 0; j < 4; ++j) bh[j] = *(const f16x8*)bptr[j];

    for (int k0 = 0; k0 < DMODEL; k0 += 32) {
        {
            f16x8 h;
            h[0] = (_Float16)a0.x; h[1] = (_Float16)a0.y;
            h[2] = (_Float16)a0.z; h[3] = (_Float16)a0.w;
            h[4] = (_Float16)a1.x; h[5] = (_Float16)a1.y;
            h[6] = (_Float16)a1.z; h[7] = (_Float16)a1.w;
            *(f16x8*)&As[arow][akq] = h;
        }
        #pragma unroll
        for (int j = 0; j < 4; ++j) *(f16x8*)&Bs[bn[j]][bkc[j]] = bh[j];
        __syncthreads();

        if (k0 + 32 < DMODEL) {   // issue next K-step's loads before MFMA
            a0 = *(const float4*)(const void*)(aptr + k0 + 32);
            a1 = *(const float4*)(const void*)(aptr + k0 + 36);
            #pragma unroll
            for (int j = 0; j < 4; ++j) bh[j] = *(const f16x8*)(bptr[j] + k0 + 32);
        }

        f16x8 af[4], bf[4];
        #pragma unroll
        for (int mi = 0; mi < 4; ++mi)
            af[mi] = *(const f16x8*)&As[mi * 16 + l15][l16 * 8];
        #pragma unroll
        for (int ni = 0; ni < 4; ++ni)
            bf[ni] = *(const f16x8*)&Bs[wave * 64 + ni * 16 + l15][l16 * 8];
        #pragma unroll
        for (int mi = 0; mi < 4; ++mi)
            #pragma unroll
            for (int ni = 0; ni < 4; ++ni)
                acc[mi][ni] = __builtin_amdgcn_mfma_f32_16x16x32_f16(
                    af[mi], bf[ni], acc[mi][ni], 0, 0, 0);
        __syncthreads();
    }

    if (isval) {
        // ---- epilogue A: LDS bounce -> coalesced head-major stores
        _Float16 (*out_s)[LDSW] = (_Float16 (*)[LDSW])smem;
        const int cell = tid >> 2, dchunk = tid & 3;
        #pragma unroll
        for (int hh = 0; hh < 2; ++hh) {
            if ((wave >> 1) == hh) {
                int cb = (wave & 1) * 64;
                #pragma unroll
                for (int ni = 0; ni < 4; ++ni) {
                    int col = wave * 64 + ni * 16 + l15;
                    float b = bval[col];
                    #pragma unroll
                    for (int mi = 0; mi < 4; ++mi)
                        #pragma unroll
                        for (int j = 0; j < 4; ++j)
                            out_s[mi * 16 + l16 * 4 + j][cb + ni * 16 + l15] =
                                (_Float16)(acc[mi][ni][j] + b);
                }
            }
            __syncthreads();
            #pragma unroll
            for (int h2 = 0; h2 < 4; ++h2) {
                int h = hh * 4 + h2;
                f16x4 lo = *(const f16x4*)&out_s[cell][h2 * 32 + dchunk * 8];
                f16x4 hi = *(const f16x4*)&out_s[cell][h2 * 32 + dchunk * 8 + 4];
                size_t base = ((size_t)h * LENIN + brow + cell) * DHEAD + dchunk * 8;
                *(f16x4*)&valueH[base]     = lo;
                *(f16x4*)&valueH[base + 4] = hi;
            }
            __syncthreads();
        }
    } else {
        // ---- epilogue B: f16 stores to proj
        #pragma unroll
        for (int ni = 0; ni < 4; ++ni) {
            int col = ncb + wave * 64 + ni * 16 + l15;
            float b = (col < NOFF) ? boff[col] : batt[col - NOFF];
            #pragma unroll
            for (int mi = 0; mi < 4; ++mi)
                #pragma unroll
                for (int j = 0; j < 4; ++j) {
                    int row = brow + mi * 16 + l16 * 4 + j;
                    if (row < NQ)
                        proj[(size_t)row * NPROJ + col] = (_Float16)(acc[mi][ni][j] + b);
                }
        }
    }
}

// -------- sampler v7: ONE head per block, v4/v6 gather structure unchanged.
// grid = 125 query-groups x 8 heads; head = bid & 7 -> with round-robin
// block->XCD dispatch each XCD serves ONE head: working set 2.4 MB < 4 MB L2.
// Block: 32 queries x 1 head; wave = 8 queries; lane = q3(3b)|s(3b).
// Per-lane gather work identical to v4/v6 (64 x 16B loads, 1 shfl).
__global__ __launch_bounds__(256) void sample_fused7(
    const _Float16* __restrict__ value, const _Float16* __restrict__ proj,
    const float* __restrict__ refpts, _Float16* __restrict__ oat)
{
    __shared__ float    loc_s[32][48];           //  6144 B
    __shared__ float    aw_s [32][16];           //  2048 B
    __shared__ unsigned ca_s [32 * CTB];         // 16896 B
    __shared__ _Float16 cw_s [32 * CTB];         //  8448 B
    // total 33536 B -> 4 blocks/CU

    const int tid  = threadIdx.x;
    const int wv   = tid >> 6, lane = tid & 63;
    const int head = blockIdx.x & 7;             // XCD-stable head
    const int q0   = (blockIdx.x >> 3) * 32;

    // ---- phase 0a: locations (32q x 48 = 1536 jobs)
    #pragma unroll
    for (int it = 0; it < 6; ++it) {
        int id = it * 256 + tid;
        int lq = id / 48, c = id - lq * 48;
        int pt = c / 3,   ax = c - pt * 3, lvl = pt >> 2;
        int q = q0 + lq;
        float v = (float)proj[(size_t)q * NPROJ + head * 48 + c];
        float norm = (float)(32 >> lvl);
        loc_s[lq][c] = refpts[((size_t)q * NLVL + lvl) * 3 + ax] + v / norm;
    }
    // ---- phase 0b: softmax (32q x 16 = 512 jobs, 16-lane groups)
    #pragma unroll
    for (int it = 0; it < 2; ++it) {
        int id = it * 256 + tid;
        int lq = id >> 4, j = id & 15;
        int q = q0 + lq;
        float v = (float)proj[(size_t)q * NPROJ + NOFF + head * 16 + j];
        float m = v;
        #pragma unroll
        for (int o = 8; o >= 1; o >>= 1) m = fmaxf(m, __shfl_xor(m, o, 16));
        float e = expf(v - m);
        float s = e;
        #pragma unroll
        for (int o = 8; o >= 1; o >>= 1) s += __shfl_xor(s, o, 16);
        aw_s[lq][j] = e / s;
    }
    __syncthreads();

    // ---- phase 1: corner table (32q x 16pt x 8c = 4096 jobs, 16 iters)
    #pragma unroll
    for (int k = 0; k < 16; ++k) {
        int id = k * 256 + tid;
        int lq = id >> 7, pt = (id >> 3) & 15, c = id & 7;
        int lvl = pt >> 2;
        int S = 32 >> lvl;
        float Sf = (float)S;
        int base = (lvl == 0) ? 0 : (lvl == 1) ? 32768 : (lvl == 2) ? 36864 : 37376;

        float lx = loc_s[lq][pt * 3 + 0];
        float ly = loc_s[lq][pt * 3 + 1];
        float lz = loc_s[lq][pt * 3 + 2];
        float aw = aw_s[lq][pt];

        float x = lx * Sf - 0.5f, y = ly * Sf - 0.5f, z = lz * Sf - 0.5f;
        float x0f = floorf(x), y0f = floorf(y), z0f = floorf(z);
        float fx = x - x0f, fy = y - y0f, fz = z - z0f;
        int dx = c & 1, dy = (c >> 1) & 1, dz = c >> 2;
        int xi = (int)x0f + dx, yi = (int)y0f + dy, zi = (int)z0f + dz;
        float wx = dx ? fx : 1.f - fx;
        float wy = dy ? fy : 1.f - fy;
        float wz = dz ? fz : 1.f - fz;
        bool valid = (unsigned)xi < (unsigned)S &&
                     (unsigned)yi < (unsigned)S &&
                     (unsigned)zi < (unsigned)S;
        int idx = (zi * S + yi) * S + xi;            // meaningful iff valid
        unsigned addr = valid ? (unsigned)(base + idx) * 64u : 0u;
        float w = valid ? wx * wy * wz * aw : 0.f;
        ca_s[lq * CTB + pt * 8 + c] = addr;
        cw_s[lq * CTB + pt * 8 + c] = (_Float16)w;
    }
    __syncthreads();

    // ---- phase 2: gather (identical structure to v4/v6; 64 x 16B loads/lane)
    const int q3 = lane >> 3, s = lane & 7;
    const int chunk = s & 3, half4 = (s >> 2) * 4;
    const int lq = wv * 8 + q3;
    const char* vb = (const char*)(value + (size_t)head * LENIN * DHEAD) + chunk * 16;
    const unsigned* ca  = &ca_s[lq * CTB];
    const _Float16* cwp = &cw_s[lq * CTB];

    float acc[8] = {};
    #pragma unroll 4
    for (int pt = 0; pt < 16; ++pt) {
        uint4 a4 = *(const uint4*)&ca[pt * 8 + half4];
        f16x4 w4 = *(const f16x4*)&cwp[pt * 8 + half4];
        {
            f16x8 v = *(const f16x8*)(vb + a4.x); float w = (float)w4[0];
            #pragma unroll
            for (int j = 0; j < 8; ++j) acc[j] += w * (float)v[j];
        }
        {
            f16x8 v = *(const f16x8*)(vb + a4.y); float w = (float)w4[1];
            #pragma unroll
            for (int j = 0; j < 8; ++j) acc[j] += w * (float)v[j];
        }
        {
            f16x8 v = *(const f16x8*)(vb + a4.z); float w = (float)w4[2];
            #pragma unroll
            for (int j = 0; j < 8; ++j) acc[j] += w * (float)v[j];
        }
        {
            f16x8 v = *(const f16x8*)(vb + a4.w); float w = (float)w4[3];
            #pragma unroll
            for (int j = 0; j < 8; ++j) acc[j] += w * (float)v[j];
        }
    }
    // combine the two corner-halves (lanes s and s^4 own same channels)
    #pragma unroll
    for (int j = 0; j < 8; ++j) acc[j] += __shfl_xor(acc[j], 4);

    if (s < 4) {
        f16x8 r;
        #pragma unroll
        for (int j = 0; j < 8; ++j) r[j] = (_Float16)acc[j];
        *(f16x8*)&oat[(size_t)(q0 + lq) * DMODEL + head * DHEAD + chunk * 8] = r;
    }
}

// ---------------------- output projection (f16 in, MFMA, 64x128 per block)
__global__ __launch_bounds__(256) void gemm_out(
    const _Float16* __restrict__ A, const _Float16* __restrict__ BT,
    const float* __restrict__ bias, float* __restrict__ C)
{
    __shared__ __align__(16) _Float16 As[64][LDH];
    __shared__ __align__(16) _Float16 Bs[128][LDH];
    const int tid  = threadIdx.x;
    const int wave = tid >> 6, lane = tid & 63;
    const int brow = blockIdx.x * 64;
    const int bcol = blockIdx.y * 128;
    const int l15 = lane & 15, l16 = lane >> 4;

    const int arow = tid >> 2, akq = (tid & 3) * 8;
    int arg = brow + arow; if (arg >= NQ) arg = NQ - 1;
    const _Float16* aptr = A + (size_t)arg * DMODEL + akq;

    const _Float16* bptr[2];
    int bn[2], bkc[2];
    #pragma unroll
    for (int j = 0; j < 2; ++j) {
        int id = tid + 256 * j;
        bn[j] = id >> 2; bkc[j] = (id & 3) * 8;
        bptr[j] = BT + (size_t)(bcol + bn[j]) * DMODEL + bkc[j];
    }

    f32x4 acc[4][2] = {};
    f16x8 ah, bh[2];
    ah = *(const f16x8*)(const void*)aptr;
    #pragma unroll
    for (int j = 0; j < 2; ++j) bh[j] = *(const f16x8*)bptr[j];

    for (int k0 = 0; k0 < DMODEL; k0 += 32) {
        *(f16x8*)&As[arow][akq] = ah;
        #pragma unroll
        for (int j = 0; j < 2; ++j) *(f16x8*)&Bs[bn[j]][bkc[j]] = bh[j];
        __syncthreads();

        if (k0 + 32 < DMODEL) {
            ah = *(const f16x8*)(const void*)(aptr + k0 + 32);
            #pragma unroll
            for (int j = 0; j < 2; ++j) bh[j] = *(const f16x8*)(bptr[j] + k0 + 32);
        }

        f16x8 af[4], bf[2];
        #pragma unroll
        for (int mi = 0; mi < 4; ++mi)
            af[mi] = *(const f16x8*)&As[mi * 16 + l15][l16 * 8];
        #pragma unroll
        for (int ni = 0; ni < 2; ++ni)
            bf[ni] = *(const f16x8*)&Bs[wave * 32 + ni * 16 + l15][l16 * 8];
        #pragma unroll
        for (int mi = 0; mi < 4; ++mi)
            #pragma unroll
            for (int ni = 0; ni < 2; ++ni)
                acc[mi][ni] = __builtin_amdgcn_mfma_f32_16x16x32_f16(
                    af[mi], bf[ni], acc[mi][ni], 0, 0, 0);
        __syncthreads();
    }

    #pragma unroll
    for (int ni = 0; ni < 2; ++ni) {
        int col = bcol + wave * 32 + ni * 16 + l15;
        float b = bias[col];
        #pragma unroll
        for (int mi = 0; mi < 4; ++mi)
            #pragma unroll
            for (int j = 0; j < 4; ++j) {
                int row = brow + mi * 16 + l16 * 4 + j;
                if (row < NQ)
                    C[(size_t)row * DMODEL + col] = acc[mi][ni][j] + b;
            }
    }
}

extern "C" void kernel_launch(void* const* d_in, const int* in_sizes, int n_in,
                              void* d_out, int out_size, void* d_ws, size_t ws_size,
                              hipStream_t stream) {
    const float* query         = (const float*)d_in[0];
    const float* refpts        = (const float*)d_in[1];
    const float* input_flatten = (const float*)d_in[2];
    const float* w_value       = (const float*)d_in[3];
    const float* b_value       = (const float*)d_in[4];
    const float* w_off         = (const float*)d_in[5];
    const float* b_off         = (const float*)d_in[6];
    const float* w_attn        = (const float*)d_in[7];
    const float* b_attn        = (const float*)d_in[8];
    const float* w_out         = (const float*)d_in[9];
    const float* b_out         = (const float*)d_in[10];

    _Float16* valueH = (_Float16*)d_ws;                    // head-major [h][cell][32]
    _Float16* wvT    = valueH + (size_t)LENIN * DMODEL;
    _Float16* catT   = wvT + 256 * 256;
    _Float16* wuT    = catT + 512 * 256;
    _Float16* proj   = wuT + 256 * 256;                    // f16 [NQ][512]
    _Float16* oatH   = proj + (size_t)NQ * NPROJ;
    // total ~26 MB of workspace

    cast_transpose_all<<<dim3(16, 4), 256, 0, stream>>>(
        w_value, w_off, w_attn, w_out, wvT, catT, wuT);

    gemm_front<<<NVBLK + NQBLK * 2, 256, 0, stream>>>(
        input_flatten, query, wvT, catT, b_value, b_off, b_attn, valueH, proj);

    sample_fused7<<<1000, 256, 0, stream>>>(valueH, proj, refpts, oatH);

    gemm_out<<<dim3(NQBLK, 2), 256, 0, stream>>>(oatH, wuT, b_out, (float*)d_out);
}

// Round 15
// 60.265 us; speedup vs baseline: 1.3723x; 1.0014x over previous
//
#include <hip/hip_runtime.h>
#include <hip/hip_bf16.h>

#define NQ     4000
#define DMODEL 256
#define NHEAD  8
#define NLVL   4
#define NPT    4
#define DHEAD  32
#define LENIN  37440
#define NOFF   384
#define NATT   128
#define NPROJ  512   // NOFF + NATT

#define NVBLK  (LENIN / 64)            // 585 value-role blocks
#define NQBLK  ((NQ + 63) / 64)        // 63 row tiles for query-side GEMMs
#define LDH    40                      // padded LDS row (halfs) for GEMM tiles
#define LDSW   132                     // padded LDS row (halfs) for C bounce
#define CTB    132                     // padded corner-table stride (entries)

typedef _Float16 f16x8 __attribute__((ext_vector_type(8)));
typedef _Float16 f16x4 __attribute__((ext_vector_type(4)));
typedef float    f32x4 __attribute__((ext_vector_type(4)));

// ------------------------------------- all weight casts+transposes, 1 launch
__global__ __launch_bounds__(256) void cast_transpose_all(
    const float* __restrict__ wv, const float* __restrict__ wo,
    const float* __restrict__ wa, const float* __restrict__ wu,
    _Float16* __restrict__ wvT, _Float16* __restrict__ catT,
    _Float16* __restrict__ wuT)
{
    __shared__ float t[64][65];
    const int xt = blockIdx.x, kt = blockIdx.y;
    const float* W; _Float16* WT; int ncols, col0, nbase;
    if (xt < 4)       { W = wv; WT = wvT;  ncols = 256; col0 = xt * 64;        nbase = col0; }
    else if (xt < 10) { W = wo; WT = catT; ncols = 384; col0 = (xt - 4) * 64;  nbase = col0; }
    else if (xt < 12) { W = wa; WT = catT; ncols = 128; col0 = (xt - 10) * 64; nbase = 384 + col0; }
    else              { W = wu; WT = wuT;  ncols = 256; col0 = (xt - 12) * 64; nbase = col0; }

    const int by = kt * 64;           // k-range
    const int tid = threadIdx.x;
    const int c = tid & 63, r0 = tid >> 6;
    #pragma unroll
    for (int i = 0; i < 16; ++i) {
        int r = r0 + i * 4;
        t[r][c] = W[(size_t)(by + r) * ncols + col0 + c];
    }
    __syncthreads();
    #pragma unroll
    for (int i = 0; i < 16; ++i) {
        int n = r0 + i * 4;
        WT[(size_t)(nbase + n) * DMODEL + by + c] = (_Float16)t[c][n];
    }
}

// -------------------------------------------- merged front GEMM (fp32 input)
__global__ __launch_bounds__(256) void gemm_front(
    const float* __restrict__ Aval, const float* __restrict__ query,
    const _Float16* __restrict__ wvT, const _Float16* __restrict__ catT,
    const float* __restrict__ bval, const float* __restrict__ boff,
    const float* __restrict__ batt,
    _Float16* __restrict__ valueH, _Float16* __restrict__ proj)
{
    __shared__ __align__(16) char smem[25600];
    _Float16 (*As)[LDH] = (_Float16 (*)[LDH])smem;                 // 64 x 40
    _Float16 (*Bs)[LDH] = (_Float16 (*)[LDH])(smem + 64 * LDH * 2);// 256 x 40

    const int tid  = threadIdx.x;
    const int wave = tid >> 6, lane = tid & 63;
    const int l15 = lane & 15, l16 = lane >> 4;

    const int  bid   = blockIdx.x;
    const bool isval = (bid < NVBLK);
    const float* A; const _Float16* BT; int brow, ncb, M;
    if (isval) { A = Aval;  BT = wvT;  brow = bid * 64;  ncb = 0;  M = LENIN; }
    else       { int idx = bid - NVBLK; A = query; BT = catT;
                 brow = (idx >> 1) * 64; ncb = (idx & 1) * 256; M = NQ; }

    const int arow = tid >> 2, akq = (tid & 3) * 8;
    int arg = brow + arow; if (arg >= M) arg = M - 1;
    const float* aptr = A + (size_t)arg * DMODEL + akq;

    const _Float16* bptr[4];
    int bn[4], bkc[4];
    #pragma unroll
    for (int j = 0; j < 4; ++j) {
        int id = tid + 256 * j;            // chunk id = n*4 + kc
        bn[j] = id >> 2; bkc[j] = (id & 3) * 8;
        bptr[j] = BT + (size_t)(ncb + bn[j]) * DMODEL + bkc[j];
    }

    f32x4 acc[4][4] = {};   // [mi][ni]
    float4 a0, a1;
    f16x8 bh[4];

    a0 = *(const float4*)(const void*)aptr;
    a1 = *(const float4*)(const void*)(aptr + 4);
    #pragma unroll
    for (int j = 0; j < 4; ++j) bh[j] = *(const f16x8*)bptr[j];

    for (int k0 = 0; k0 < DMODEL; k0 += 32) {
        {
            f16x8 h;
            h[0] = (_Float16)a0.x; h[1] = (_Float16)a0.y;
            h[2] = (_Float16)a0.z; h[3] = (_Float16)a0.w;
            h[4] = (_Float16)a1.x; h[5] = (_Float16)a1.y;
            h[6] = (_Float16)a1.z; h[7] = (_Float16)a1.w;
            *(f16x8*)&As[arow][akq] = h;
        }
        #pragma unroll
        for (int j = 0; j < 4; ++j) *(f16x8*)&Bs[bn[j]][bkc[j]] = bh[j];
        __syncthreads();

        if (k0 + 32 < DMODEL) {   // issue next K-step's loads before MFMA
            a0 = *(const float4*)(const void*)(aptr + k0 + 32);
            a1 = *(const float4*)(const void*)(aptr + k0 + 36);
            #pragma unroll
            for (int j = 0; j < 4; ++j) bh[j] = *(const f16x8*)(bptr[j] + k0 + 32);
        }

        f16x8 af[4], bf[4];
        #pragma unroll
        for (int mi = 0; mi < 4; ++mi)
            af[mi] = *(const f16x8*)&As[mi * 16 + l15][l16 * 8];
        #pragma unroll
        for (int ni = 0; ni < 4; ++ni)
            bf[ni] = *(const f16x8*)&Bs[wave * 64 + ni * 16 + l15][l16 * 8];
        #pragma unroll
        for (int mi = 0; mi < 4; ++mi)
            #pragma unroll
            for (int ni = 0; ni < 4; ++ni)
                acc[mi][ni] = __builtin_amdgcn_mfma_f32_16x16x32_f16(
                    af[mi], bf[ni], acc[mi][ni], 0, 0, 0);
        __syncthreads();
    }

    if (isval) {
        // ---- epilogue A: LDS bounce -> coalesced head-major stores
        _Float16 (*out_s)[LDSW] = (_Float16 (*)[LDSW])smem;
        const int cell = tid >> 2, dchunk = tid & 3;
        #pragma unroll
        for (int hh = 0; hh < 2; ++hh) {
            if ((wave >> 1) == hh) {
                int cb = (wave & 1) * 64;
                #pragma unroll
                for (int ni = 0; ni < 4; ++ni) {
                    int col = wave * 64 + ni * 16 + l15;
                    float b = bval[col];
                    #pragma unroll
                    for (int mi = 0; mi < 4; ++mi)
                        #pragma unroll
                        for (int j = 0; j < 4; ++j)
                            out_s[mi * 16 + l16 * 4 + j][cb + ni * 16 + l15] =
                                (_Float16)(acc[mi][ni][j] + b);
                }
            }
            __syncthreads();
            #pragma unroll
            for (int h2 = 0; h2 < 4; ++h2) {
                int h = hh * 4 + h2;
                f16x4 lo = *(const f16x4*)&out_s[cell][h2 * 32 + dchunk * 8];
                f16x4 hi = *(const f16x4*)&out_s[cell][h2 * 32 + dchunk * 8 + 4];
                size_t base = ((size_t)h * LENIN + brow + cell) * DHEAD + dchunk * 8;
                *(f16x4*)&valueH[base]     = lo;
                *(f16x4*)&valueH[base + 4] = hi;
            }
            __syncthreads();
        }
    } else {
        // ---- epilogue B: f16 stores to proj
        #pragma unroll
        for (int ni = 0; ni < 4; ++ni) {
            int col = ncb + wave * 64 + ni * 16 + l15;
            float b = (col < NOFF) ? boff[col] : batt[col - NOFF];
            #pragma unroll
            for (int mi = 0; mi < 4; ++mi)
                #pragma unroll
                for (int j = 0; j < 4; ++j) {
                    int row = brow + mi * 16 + l16 * 4 + j;
                    if (row < NQ)
                        proj[(size_t)row * NPROJ + col] = (_Float16)(acc[mi][ni][j] + b);
                }
        }
    }
}

// -------- sampler v8: v7 + x-pair corner-table permutation.
// Table position pt*8 + (c&1)*4 + (c>>1) holds corner c, so gather
// instruction j makes lanes 0-3 load corner 2j and lanes 4-7 its x-neighbor
// corner 2j+1 -> per query per instruction one contiguous 128B span
// (two adjacent 64B cells) instead of two scattered cells.
__global__ __launch_bounds__(256) void sample_fused8(
    const _Float16* __restrict__ value, const _Float16* __restrict__ proj,
    const float* __restrict__ refpts, _Float16* __restrict__ oat)
{
    __shared__ float    loc_s[32][48];           //  6144 B
    __shared__ float    aw_s [32][16];           //  2048 B
    __shared__ unsigned ca_s [32 * CTB];         // 16896 B
    __shared__ _Float16 cw_s [32 * CTB];         //  8448 B
    // total 33536 B -> 4 blocks/CU

    const int tid  = threadIdx.x;
    const int wv   = tid >> 6, lane = tid & 63;
    const int head = blockIdx.x & 7;             // XCD-stable head
    const int q0   = (blockIdx.x >> 3) * 32;

    // ---- phase 0a: locations (32q x 48 = 1536 jobs)
    #pragma unroll
    for (int it = 0; it < 6; ++it) {
        int id = it * 256 + tid;
        int lq = id / 48, c = id - lq * 48;
        int pt = c / 3,   ax = c - pt * 3, lvl = pt >> 2;
        int q = q0 + lq;
        float v = (float)proj[(size_t)q * NPROJ + head * 48 + c];
        float norm = (float)(32 >> lvl);
        loc_s[lq][c] = refpts[((size_t)q * NLVL + lvl) * 3 + ax] + v / norm;
    }
    // ---- phase 0b: softmax (32q x 16 = 512 jobs, 16-lane groups)
    #pragma unroll
    for (int it = 0; it < 2; ++it) {
        int id = it * 256 + tid;
        int lq = id >> 4, j = id & 15;
        int q = q0 + lq;
        float v = (float)proj[(size_t)q * NPROJ + NOFF + head * 16 + j];
        float m = v;
        #pragma unroll
        for (int o = 8; o >= 1; o >>= 1) m = fmaxf(m, __shfl_xor(m, o, 16));
        float e = expf(v - m);
        float s = e;
        #pragma unroll
        for (int o = 8; o >= 1; o >>= 1) s += __shfl_xor(s, o, 16);
        aw_s[lq][j] = e / s;
    }
    __syncthreads();

    // ---- phase 1: corner table (32q x 16pt x 8c = 4096 jobs, 16 iters)
    #pragma unroll
    for (int k = 0; k < 16; ++k) {
        int id = k * 256 + tid;
        int lq = id >> 7, pt = (id >> 3) & 15, c = id & 7;
        int lvl = pt >> 2;
        int S = 32 >> lvl;
        float Sf = (float)S;
        int base = (lvl == 0) ? 0 : (lvl == 1) ? 32768 : (lvl == 2) ? 36864 : 37376;

        float lx = loc_s[lq][pt * 3 + 0];
        float ly = loc_s[lq][pt * 3 + 1];
        float lz = loc_s[lq][pt * 3 + 2];
        float aw = aw_s[lq][pt];

        float x = lx * Sf - 0.5f, y = ly * Sf - 0.5f, z = lz * Sf - 0.5f;
        float x0f = floorf(x), y0f = floorf(y), z0f = floorf(z);
        float fx = x - x0f, fy = y - y0f, fz = z - z0f;
        int dx = c & 1, dy = (c >> 1) & 1, dz = c >> 2;
        int xi = (int)x0f + dx, yi = (int)y0f + dy, zi = (int)z0f + dz;
        float wx = dx ? fx : 1.f - fx;
        float wy = dy ? fy : 1.f - fy;
        float wz = dz ? fz : 1.f - fz;
        bool valid = (unsigned)xi < (unsigned)S &&
                     (unsigned)yi < (unsigned)S &&
                     (unsigned)zi < (unsigned)S;
        int idx = (zi * S + yi) * S + xi;            // meaningful iff valid
        unsigned addr = valid ? (unsigned)(base + idx) * 64u : 0u;
        float w = valid ? wx * wy * wz * aw : 0.f;
        int pos = pt * 8 + ((c & 1) << 2) + (c >> 1);   // x-pair permutation
        ca_s[lq * CTB + pos] = addr;
        cw_s[lq * CTB + pos] = (_Float16)w;
    }
    __syncthreads();

    // ---- phase 2: gather (same instruction structure; instruction j now
    //      touches the x-pair (2j, 2j+1) -> contiguous 128B per query)
    const int q3 = lane >> 3, s = lane & 7;
    const int chunk = s & 3, half4 = (s >> 2) * 4;
    const int lq = wv * 8 + q3;
    const char* vb = (const char*)(value + (size_t)head * LENIN * DHEAD) + chunk * 16;
    const unsigned* ca  = &ca_s[lq * CTB];
    const _Float16* cwp = &cw_s[lq * CTB];

    float acc[8] = {};
    #pragma unroll 4
    for (int pt = 0; pt < 16; ++pt) {
        uint4 a4 = *(const uint4*)&ca[pt * 8 + half4];
        f16x4 w4 = *(const f16x4*)&cwp[pt * 8 + half4];
        {
            f16x8 v = *(const f16x8*)(vb + a4.x); float w = (float)w4[0];
            #pragma unroll
            for (int j = 0; j < 8; ++j) acc[j] += w * (float)v[j];
        }
        {
            f16x8 v = *(const f16x8*)(vb + a4.y); float w = (float)w4[1];
            #pragma unroll
            for (int j = 0; j < 8; ++j) acc[j] += w * (float)v[j];
        }
        {
            f16x8 v = *(const f16x8*)(vb + a4.z); float w = (float)w4[2];
            #pragma unroll
            for (int j = 0; j < 8; ++j) acc[j] += w * (float)v[j];
        }
        {
            f16x8 v = *(const f16x8*)(vb + a4.w); float w = (float)w4[3];
            #pragma unroll
            for (int j = 0; j < 8; ++j) acc[j] += w * (float)v[j];
        }
    }
    // combine the two corner-halves (lanes s and s^4 own same channels)
    #pragma unroll
    for (int j = 0; j < 8; ++j) acc[j] += __shfl_xor(acc[j], 4);

    if (s < 4) {
        f16x8 r;
        #pragma unroll
        for (int j = 0; j < 8; ++j) r[j] = (_Float16)acc[j];
        *(f16x8*)&oat[(size_t)(q0 + lq) * DMODEL + head * DHEAD + chunk * 8] = r;
    }
}

// ---------------------- output projection (f16 in, MFMA, 64x128 per block)
__global__ __launch_bounds__(256) void gemm_out(
    const _Float16* __restrict__ A, const _Float16* __restrict__ BT,
    const float* __restrict__ bias, float* __restrict__ C)
{
    __shared__ __align__(16) _Float16 As[64][LDH];
    __shared__ __align__(16) _Float16 Bs[128][LDH];
    const int tid  = threadIdx.x;
    const int wave = tid >> 6, lane = tid & 63;
    const int brow = blockIdx.x * 64;
    const int bcol = blockIdx.y * 128;
    const int l15 = lane & 15, l16 = lane >> 4;

    const int arow = tid >> 2, akq = (tid & 3) * 8;
    int arg = brow + arow; if (arg >= NQ) arg = NQ - 1;
    const _Float16* aptr = A + (size_t)arg * DMODEL + akq;

    const _Float16* bptr[2];
    int bn[2], bkc[2];
    #pragma unroll
    for (int j = 0; j < 2; ++j) {
        int id = tid + 256 * j;
        bn[j] = id >> 2; bkc[j] = (id & 3) * 8;
        bptr[j] = BT + (size_t)(bcol + bn[j]) * DMODEL + bkc[j];
    }

    f32x4 acc[4][2] = {};
    f16x8 ah, bh[2];
    ah = *(const f16x8*)(const void*)aptr;
    #pragma unroll
    for (int j = 0; j < 2; ++j) bh[j] = *(const f16x8*)bptr[j];

    for (int k0 = 0; k0 < DMODEL; k0 += 32) {
        *(f16x8*)&As[arow][akq] = ah;
        #pragma unroll
        for (int j = 0; j < 2; ++j) *(f16x8*)&Bs[bn[j]][bkc[j]] = bh[j];
        __syncthreads();

        if (k0 + 32 < DMODEL) {
            ah = *(const f16x8*)(const void*)(aptr + k0 + 32);
            #pragma unroll
            for (int j = 0; j < 2; ++j) bh[j] = *(const f16x8*)(bptr[j] + k0 + 32);
        }

        f16x8 af[4], bf[2];
        #pragma unroll
        for (int mi = 0; mi < 4; ++mi)
            af[mi] = *(const f16x8*)&As[mi * 16 + l15][l16 * 8];
        #pragma unroll
        for (int ni = 0; ni < 2; ++ni)
            bf[ni] = *(const f16x8*)&Bs[wave * 32 + ni * 16 + l15][l16 * 8];
        #pragma unroll
        for (int mi = 0; mi < 4; ++mi)
            #pragma unroll
            for (int ni = 0; ni < 2; ++ni)
                acc[mi][ni] = __builtin_amdgcn_mfma_f32_16x16x32_f16(
                    af[mi], bf[ni], acc[mi][ni], 0, 0, 0);
        __syncthreads();
    }

    #pragma unroll
    for (int ni = 0; ni < 2; ++ni) {
        int col = bcol + wave * 32 + ni * 16 + l15;
        float b = bias[col];
        #pragma unroll
        for (int mi = 0; mi < 4; ++mi)
            #pragma unroll
            for (int j = 0; j < 4; ++j) {
                int row = brow + mi * 16 + l16 * 4 + j;
                if (row < NQ)
                    C[(size_t)row * DMODEL + col] = acc[mi][ni][j] + b;
            }
    }
}

extern "C" void kernel_launch(void* const* d_in, const int* in_sizes, int n_in,
                              void* d_out, int out_size, void* d_ws, size_t ws_size,
                              hipStream_t stream) {
    const float* query         = (const float*)d_in[0];
    const float* refpts        = (const float*)d_in[1];
    const float* input_flatten = (const float*)d_in[2];
    const float* w_value       = (const float*)d_in[3];
    const float* b_value       = (const float*)d_in[4];
    const float* w_off         = (const float*)d_in[5];
    const float* b_off         = (const float*)d_in[6];
    const float* w_attn        = (const float*)d_in[7];
    const float* b_attn        = (const float*)d_in[8];
    const float* w_out         = (const float*)d_in[9];
    const float* b_out         = (const float*)d_in[10];

    _Float16* valueH = (_Float16*)d_ws;                    // head-major [h][cell][32]
    _Float16* wvT    = valueH + (size_t)LENIN * DMODEL;
    _Float16* catT   = wvT + 256 * 256;
    _Float16* wuT    = catT + 512 * 256;
    _Float16* proj   = wuT + 256 * 256;                    // f16 [NQ][512]
    _Float16* oatH   = proj + (size_t)NQ * NPROJ;
    // total ~26 MB of workspace

    cast_transpose_all<<<dim3(16, 4), 256, 0, stream>>>(
        w_value, w_off, w_attn, w_out, wvT, catT, wuT);

    gemm_front<<<NVBLK + NQBLK * 2, 256, 0, stream>>>(
        input_flatten, query, wvT, catT, b_value, b_off, b_attn, valueH, proj);

    sample_fused8<<<1000, 256, 0, stream>>>(valueH, proj, refpts, oatH);

    gemm_out<<<dim3(NQBLK, 2), 256, 0, stream>>>(oatH, wuT, b_out, (float*)d_out);
}